// Round 13
// baseline (1260.031 us; speedup 1.0000x reference)
//
#include <hip/hip_runtime.h>
#include <hip/hip_bf16.h>
#include <cstdint>
#include <cstddef>

// ---------------------------------------------------------------------------
// SemanticTransformer forward. bf16 MFMA compute, f32 residual stream.
// Round 20: 64-row fused LN kernels. r18/r19's 16-row fused tiles read the
// full weight per wg (W2: 768 MB L2 B-traffic vs 192 at 64-row tiles).
// k_gmm_ln and k_mprojc now use 64-row wgs (grid M/64): each wave computes
// its 16 rows x all 256 cols (acc[4][4]); LN row-sums reduced IN REGISTERS
// via 4 shfl_xor (no LDS Ot round-trip). Inner loops single-buffered to
// stay under the 128-VGPR (256,4) budget. k_mprojc phase-1 combine runs 4
// passes of 16 rows into a 32KB swizzled At. Everything else from r19.
// B=2, N=2048, C=256, NHEAD=4, DH=64, D2=384, G=16, Lp=512, layers=5
// ---------------------------------------------------------------------------

typedef __attribute__((ext_vector_type(8))) short bf16x8;   // 8 bf16, 4 VGPRs
typedef __attribute__((ext_vector_type(4))) float f32x4;

__device__ __forceinline__ float b2f(unsigned short u) {
  union { unsigned int i; float f; } v; v.i = ((unsigned int)u) << 16; return v.f;
}
__device__ __forceinline__ unsigned short f2b(float f) {
  __hip_bfloat16 h = __float2bfloat16(f);
  union { __hip_bfloat16 h; unsigned short u; } v; v.h = h; return v.u;
}
__device__ __forceinline__ unsigned int pk2(float a, float b) {
  return (unsigned int)f2b(a) | ((unsigned int)f2b(b) << 16);
}
// raw v_exp_f32 (2^x, 1 ULP) — no OCML denormal fixup
__device__ __forceinline__ float fexp2(float x) {
#if __has_builtin(__builtin_amdgcn_exp2f)
  return __builtin_amdgcn_exp2f(x);
#else
  float r; asm("v_exp_f32 %0, %1" : "=v"(r) : "v"(x)); return r;
#endif
}

// ---------------- dtype probe ----------------------------------------------
__global__ __launch_bounds__(256) void k_probe(int* __restrict__ flag,
                                               const unsigned short* __restrict__ w,
                                               int n) {
  __shared__ int ok[256];
  const int t = threadIdx.x;
  int good = 1;
  for (int i = t; i < n; i += 256) {
    float v = fabsf(b2f(w[i]));
    if (!(v < 1e3f)) good = 0;
  }
  ok[t] = good;
  __syncthreads();
  for (int s = 128; s; s >>= 1) {
    if (t < s) ok[t] &= ok[t + s];
    __syncthreads();
  }
  if (t == 0) *flag = ok[0];   // 1 = bf16 data, 0 = f32 data
}

// ---------------- input loads ----------------------------------------------
__global__ __launch_bounds__(256) void k_load2(float* __restrict__ dF,
                                               unsigned short* __restrict__ dB,
                                               const void* __restrict__ src,
                                               int n4, const int* __restrict__ flag) {
  int i = blockIdx.x * 256 + threadIdx.x;
  if (i >= n4) return;
  float4 f;
  if (*flag) {
    ushort4 u = ((const ushort4*)src)[i];
    f.x = b2f(u.x); f.y = b2f(u.y); f.z = b2f(u.z); f.w = b2f(u.w);
  } else {
    f = ((const float4*)src)[i];
  }
  ((float4*)dF)[i] = f;
  ushort4 o; o.x = f2b(f.x); o.y = f2b(f.y); o.z = f2b(f.z); o.w = f2b(f.w);
  ((ushort4*)dB)[i] = o;
}

__global__ __launch_bounds__(256) void k_loadb(unsigned short* __restrict__ dB,
                                               const void* __restrict__ src,
                                               int n4, const int* __restrict__ flag) {
  int i = blockIdx.x * 256 + threadIdx.x;
  if (i >= n4) return;
  if (*flag) {
    ((ushort4*)dB)[i] = ((const ushort4*)src)[i];
    return;
  }
  float4 f = ((const float4*)src)[i];
  ushort4 o; o.x = f2b(f.x); o.y = f2b(f.y); o.z = f2b(f.z); o.w = f2b(f.w);
  ((ushort4*)dB)[i] = o;
}

__global__ __launch_bounds__(256) void k_store(void* __restrict__ out, size_t off,
                                               const float* __restrict__ src,
                                               int n4, const int* __restrict__ flag) {
  int i = blockIdx.x * 256 + threadIdx.x;
  if (i >= n4) return;
  float4 f = ((const float4*)src)[i];
  if (*flag) {
    ushort4 u; u.x = f2b(f.x); u.y = f2b(f.y); u.z = f2b(f.z); u.w = f2b(f.w);
    ((ushort4*)((unsigned short*)out + off))[i] = u;
  } else {
    ((float4*)((float*)out + off))[i] = f;
  }
}

// dino residual: xF += addB; xB = bf16(xF)
__global__ __launch_bounds__(256) void k_add_dino(float* __restrict__ xF,
                                                  unsigned short* __restrict__ xB,
                                                  const unsigned short* __restrict__ addB,
                                                  int n4) {
  int i = blockIdx.x * 256 + threadIdx.x;
  if (i >= n4) return;
  float4 a = ((const float4*)xF)[i];
  ushort4 u = ((const ushort4*)addB)[i];
  a.x += b2f(u.x); a.y += b2f(u.y); a.z += b2f(u.z); a.w += b2f(u.w);
  ((float4*)xF)[i] = a;
  ushort4 o; o.x = f2b(a.x); o.y = f2b(a.y); o.z = f2b(a.z); o.w = f2b(a.w);
  ((ushort4*)xB)[i] = o;
}

// ---------------- weight transpose+cast+fragment-pack ----------------------
// Output layout (per z-slice): Wpk[nblk][kstep][lane][8] bf16, where
// nblk = n>>4, kstep = k>>5, lane = (kc>>3)*16 + (n&15), kc = k&31, e = kc&7.
// A wave's MFMA B-fragment (rows n0+nb*16+l16, cols k0+quad*8..+8) is then
// one contiguous 1KB block: ((nblk*KS + kstep)*64 + lane)*8.
__global__ __launch_bounds__(256) void k_wt(unsigned short* __restrict__ Wt,
                                            const void* __restrict__ W,
                                            int K, int N, int zStride,
                                            const int* __restrict__ flag) {
  __shared__ float tile[32][33];
  const int isbf = *flag;
  const int z = blockIdx.z;
  const unsigned short* Wb = (const unsigned short*)W + (size_t)z * K * N;
  const float* Wf = (const float*)W + (size_t)z * K * N;
  unsigned short* Wo = Wt + (size_t)z * zStride;
  const int KS = K >> 5;
  const int nx = blockIdx.x * 32, ky = blockIdx.y * 32;
  const int tx = threadIdx.x & 31, ty = threadIdx.x >> 5;  // ty 0..7
#pragma unroll
  for (int i = 0; i < 4; ++i) {
    int k = ky + ty + i * 8;
    float v = isbf ? b2f(Wb[(size_t)k * N + nx + tx]) : Wf[(size_t)k * N + nx + tx];
    tile[ty + i * 8][tx] = v;
  }
  __syncthreads();
  // element (k = ky+tx, n = nx+nn); ky multiple of 32 -> kstep = ky>>5, kc = tx
  const int kstep = ky >> 5;
  const int lanehi = (tx >> 3) << 4;   // quad*16
  const int e = tx & 7;
#pragma unroll
  for (int i = 0; i < 4; ++i) {
    int nn = ty + i * 8;
    int n_ = nx + nn;
    size_t idx = ((((size_t)(n_ >> 4) * KS + kstep) << 6) + (lanehi + (n_ & 15))) * 8 + e;
    Wo[idx] = f2b(tile[tx][nn]);
  }
}

// ---------------- MFMA GEMM, compile-time K --------------------------------
// Y[arow-relative output rows][n] = relu?( A[arow] @ Wpk ).
// arow = rowOff + row; for output columns n0 >= xorColStart, arow ^= rowXor.
// A concat on K: k<K1 from A1 else A2 (for W1 [x; msg]).
// B loads are contiguous 1KB fragment blocks (packed by k_wt); A/B register
// double-buffered; XCD-chunked wg swizzle for A-stripe L2 reuse.
// qkvLog2L != 0: head-major QKV epilogue — write to
// Y + sel*(M*256) + ((nbatch*4+h)*L + tok)*64 + dh, sel = n0>>8, h = (n0>>6)&3.
template<int KTOT>
__global__ __launch_bounds__(256, 4) void k_gmm(unsigned short* __restrict__ Y, int ldy,
                                                const unsigned short* __restrict__ A1, int lda1,
                                                const unsigned short* __restrict__ A2, int lda2,
                                                int K1,
                                                const unsigned short* __restrict__ Wt,
                                                int relu, int rowOff, int rowXor,
                                                int xorColStart, int qkvLog2L) {
  constexpr int KS = KTOT >> 5;
  const int tid = threadIdx.x;
  const int wq = tid >> 6, lane = tid & 63;
  const int l16 = lane & 15, quad = lane >> 4;
  // XCD-chunked swizzle (all grids have nwg % 8 == 0): contiguous work ids
  // stay on one XCD so column-blocks sharing an A-stripe hit the same L2.
  const int gx = gridDim.x;
  const int nwg = gx * gridDim.y;
  const int lid = blockIdx.y * gx + blockIdx.x;
  const int w = (lid & 7) * (nwg >> 3) + (lid >> 3);
  const int n0 = (w % gx) * 64, m0 = (w / gx) * 64;
  const int row = m0 + wq * 16 + l16;
  int arow = rowOff + row;
  if (n0 >= xorColStart) arow ^= rowXor;

  const unsigned short* Wb0 = Wt + ((size_t)(n0 >> 4) * KS << 6) * 8 + (size_t)lane * 8;

  f32x4 acc[4];
#pragma unroll
  for (int i = 0; i < 4; ++i) acc[i] = (f32x4){0.f, 0.f, 0.f, 0.f};

  auto ldA = [&](int k0) -> bf16x8 {
    const unsigned short* ap = (k0 < K1)
        ? (A1 + (size_t)arow * lda1 + k0)
        : (A2 + (size_t)arow * lda2 + (k0 - K1));
    return *(const bf16x8*)(ap + quad * 8);
  };
  auto ldB = [&](int k0, int nb) -> bf16x8 {
    return *(const bf16x8*)(Wb0 + ((size_t)nb * KS + (k0 >> 5)) * 512);
  };

  bf16x8 a0 = ldA(0), a1;
  bf16x8 b0[4], b1[4];
#pragma unroll
  for (int nb = 0; nb < 4; ++nb) b0[nb] = ldB(0, nb);

#pragma unroll
  for (int k0 = 0; k0 < KTOT; k0 += 64) {
    a1 = ldA(k0 + 32);
#pragma unroll
    for (int nb = 0; nb < 4; ++nb) b1[nb] = ldB(k0 + 32, nb);
#pragma unroll
    for (int nb = 0; nb < 4; ++nb)
      acc[nb] = __builtin_amdgcn_mfma_f32_16x16x32_bf16(a0, b0[nb], acc[nb], 0, 0, 0);
    if (k0 + 64 < KTOT) {
      a0 = ldA(k0 + 64);
#pragma unroll
      for (int nb = 0; nb < 4; ++nb) b0[nb] = ldB(k0 + 64, nb);
    }
#pragma unroll
    for (int nb = 0; nb < 4; ++nb)
      acc[nb] = __builtin_amdgcn_mfma_f32_16x16x32_bf16(a1, b1[nb], acc[nb], 0, 0, 0);
  }

  if (qkvLog2L) {
    const int Lm = (1 << qkvLog2L) - 1;
    const int sel = n0 >> 8;
    const int hh = (n0 >> 6) & 3;
    unsigned short* base = Y + (size_t)sel * ((size_t)gridDim.y << 14);  // M*256
#pragma unroll
    for (int r = 0; r < 4; ++r) {
      const int rr = m0 + wq * 16 + quad * 4 + r;
      const int tok = rr & Lm;
      const int hi = ((rr >> qkvLog2L) << 2) + hh;
      unsigned short* yp = base + ((((size_t)hi << qkvLog2L) + tok) << 6) + l16;
#pragma unroll
      for (int nb = 0; nb < 4; ++nb) yp[nb * 16] = f2b(acc[nb][r]);
    }
  } else {
#pragma unroll
    for (int r = 0; r < 4; ++r) {
      unsigned short* yp = Y + (size_t)(m0 + wq * 16 + quad * 4 + r) * ldy + n0;
#pragma unroll
      for (int nb = 0; nb < 4; ++nb) {
        float v = acc[nb][r];
        if (relu) v = fmaxf(v, 0.f);
        yp[nb * 16 + l16] = f2b(v);
      }
    }
  }
}

// ---------------- in-register LayerNorm over 256 cols -----------------------
// Wave holds 16 rows x 256 cols as acc[cb][nb][r] (col = cb*64+nb*16+l16).
// Row sum = 16-reg sum + shfl_xor(1,2,4,8) across the 16-lane group.
__device__ __forceinline__ void ln_reg(const f32x4 acc[4][4], int r,
                                       float& mean, float& inv) {
  float s = 0.f, s2 = 0.f;
#pragma unroll
  for (int cb = 0; cb < 4; ++cb)
#pragma unroll
    for (int nb = 0; nb < 4; ++nb) {
      float v = acc[cb][nb][r];
      s += v;
      s2 = fmaf(v, v, s2);
    }
#pragma unroll
  for (int off = 8; off >= 1; off >>= 1) {
    s  += __shfl_xor(s,  off, 64);
    s2 += __shfl_xor(s2, off, 64);
  }
  mean = s * (1.f / 256.f);
  float var = s2 * (1.f / 256.f) - mean * mean;
  inv = rsqrtf(var + 1e-5f);
}

// ---------------- fused GEMM (N=256) + LayerNorm, 64-row wg ----------------
// wg = 64 rows; wave wq owns rows [R0+wq*16, +16) x ALL 256 cols
// (acc[4][4], cb = 64-col block). Grid M/64 (XCD-swizzled). LN in registers.
//   mode 1: xF[row] += norm; Yb[row] = bf16(xF[row])   (W2 + lnadd)
//   mode 2: r = b2f(xBres[row]) + norm -> out (+flag)  (W2 + lnadd_out)
template<int KTOT>
__global__ __launch_bounds__(256, 4) void k_gmm_ln(unsigned short* __restrict__ Yb,
                                                   float* __restrict__ xF,
                                                   void* __restrict__ outp, size_t outOff,
                                                   const unsigned short* __restrict__ xBres,
                                                   const unsigned short* __restrict__ A1,
                                                   int lda1,
                                                   const unsigned short* __restrict__ Wt,
                                                   int mode, const int* __restrict__ flag) {
  constexpr int KS = KTOT >> 5;
  const int tid = threadIdx.x;
  const int wq = tid >> 6, lane = tid & 63;
  const int l16 = lane & 15, quad = lane >> 4;
  const int nwg = gridDim.x;
  const int lid = blockIdx.x;
  const int w = (lid & 7) * (nwg >> 3) + (lid >> 3);
  const int R0 = w * 64;

  const unsigned short* Ap = A1 + (size_t)(R0 + wq * 16 + l16) * lda1;
  const unsigned short* Wb0 = Wt + (size_t)lane * 8;

  f32x4 acc[4][4];
#pragma unroll
  for (int cb = 0; cb < 4; ++cb)
#pragma unroll
    for (int nb = 0; nb < 4; ++nb) acc[cb][nb] = (f32x4){0.f, 0.f, 0.f, 0.f};

#pragma unroll
  for (int cb = 0; cb < 4; ++cb) {
#pragma unroll
    for (int k0 = 0; k0 < KTOT; k0 += 32) {
      bf16x8 a = *(const bf16x8*)(Ap + k0 + quad * 8);
#pragma unroll
      for (int nb = 0; nb < 4; ++nb) {
        bf16x8 b = *(const bf16x8*)(Wb0 +
            (((size_t)(cb * 4 + nb) * KS + (k0 >> 5)) << 9));
        acc[cb][nb] = __builtin_amdgcn_mfma_f32_16x16x32_bf16(a, b, acc[cb][nb], 0, 0, 0);
      }
    }
  }

#pragma unroll
  for (int r = 0; r < 4; ++r) {
    float mean, inv;
    ln_reg(acc, r, mean, inv);
    const int row = R0 + wq * 16 + quad * 4 + r;
#pragma unroll
    for (int cb = 0; cb < 4; ++cb)
#pragma unroll
      for (int nb = 0; nb < 4; ++nb) {
        const float nv = (acc[cb][nb][r] - mean) * inv;
        const size_t gr = (size_t)row * 256 + cb * 64 + nb * 16 + l16;
        if (mode == 1) {
          float rs = xF[gr] + nv;
          xF[gr] = rs;
          Yb[gr] = f2b(rs);
        } else {
          float rs = b2f(xBres[gr]) + nv;
          if (*flag) ((unsigned short*)outp)[outOff + gr] = f2b(rs);
          else       ((float*)outp)[outOff + gr] = rs;
        }
      }
  }
}

// ---------------- fused attn-combine + M-proj GEMM + LN, 64-row wg ---------
// Phase 1 (4 passes of 16 rows): combine split partials into a 32KB swizzled
// LDS A-tile (unit u^(row&7)); phase 2: K=256 GEMM, wave wq owns rows
// [R0+wq*16,+16) x all 256 cols; phase 3: in-register LN -> msgB.
__global__ __launch_bounds__(256, 4) void k_mprojc(unsigned short* __restrict__ msgB,
                                                   const float* __restrict__ pO,
                                                   const float* __restrict__ pML,
                                                   int lgL, int split, int NHt,
                                                   const unsigned short* __restrict__ Wt) {
  constexpr int KS = 8;   // K = 256
  __shared__ __align__(16) unsigned short At[64 * 32 * 8];   // 32 KB
  const int tid = threadIdx.x;
  const int wq = tid >> 6, lane = tid & 63;
  const int l16 = lane & 15, quad = lane >> 4;
  const int nwg = gridDim.x;
  const int lid = blockIdx.x;
  const int w = (lid & 7) * (nwg >> 3) + (lid >> 3);
  const int R0 = w * 64;
  const int L = 1 << lgL, Lm = L - 1;

  // ---- phase 1: combine -> At (4 passes; thread: row it*16+(tid>>4), 16-col chunk) ----
#pragma unroll
  for (int it = 0; it < 4; ++it) {
    const int i = it * 16 + (tid >> 4);   // row 0..63
    const int c = tid & 15;               // 16-col chunk; head h = c>>2
    const int gr = R0 + i;
    const int n = gr >> lgL;
    const int tok = gr & Lm;
    const int nh = n * 4 + (c >> 2);
    float M = -1e30f;
    for (int sp = 0; sp < split; ++sp)
      M = fmaxf(M, pML[(((size_t)sp * NHt + nh) * L + tok) * 2]);
    float4 a0 = {0,0,0,0}, a1 = {0,0,0,0}, a2 = {0,0,0,0}, a3 = {0,0,0,0};
    float lsum = 0.f;
    for (int sp = 0; sp < split; ++sp) {
      const float* pml = pML + (((size_t)sp * NHt + nh) * L + tok) * 2;
      float e = fexp2(pml[0] - M);
      lsum = fmaf(pml[1], e, lsum);
      const float4* po = (const float4*)(pO + (((size_t)sp * NHt + nh) * L + tok) * 64
                                         + (c & 3) * 16);
      float4 v0 = po[0], v1 = po[1], v2 = po[2], v3 = po[3];
      a0.x = fmaf(v0.x, e, a0.x); a0.y = fmaf(v0.y, e, a0.y);
      a0.z = fmaf(v0.z, e, a0.z); a0.w = fmaf(v0.w, e, a0.w);
      a1.x = fmaf(v1.x, e, a1.x); a1.y = fmaf(v1.y, e, a1.y);
      a1.z = fmaf(v1.z, e, a1.z); a1.w = fmaf(v1.w, e, a1.w);
      a2.x = fmaf(v2.x, e, a2.x); a2.y = fmaf(v2.y, e, a2.y);
      a2.z = fmaf(v2.z, e, a2.z); a2.w = fmaf(v2.w, e, a2.w);
      a3.x = fmaf(v3.x, e, a3.x); a3.y = fmaf(v3.y, e, a3.y);
      a3.z = fmaf(v3.z, e, a3.z); a3.w = fmaf(v3.w, e, a3.w);
    }
    float inv = 1.0f / lsum;
    union { unsigned short us[8]; uint4 v; } p0, p1;
    p0.us[0] = f2b(a0.x * inv); p0.us[1] = f2b(a0.y * inv);
    p0.us[2] = f2b(a0.z * inv); p0.us[3] = f2b(a0.w * inv);
    p0.us[4] = f2b(a1.x * inv); p0.us[5] = f2b(a1.y * inv);
    p0.us[6] = f2b(a1.z * inv); p0.us[7] = f2b(a1.w * inv);
    p1.us[0] = f2b(a2.x * inv); p1.us[1] = f2b(a2.y * inv);
    p1.us[2] = f2b(a2.z * inv); p1.us[3] = f2b(a2.w * inv);
    p1.us[4] = f2b(a3.x * inv); p1.us[5] = f2b(a3.y * inv);
    p1.us[6] = f2b(a3.z * inv); p1.us[7] = f2b(a3.w * inv);
    const int u0 = (2 * c) ^ (i & 7);
    const int u1 = (2 * c + 1) ^ (i & 7);
    *(uint4*)&At[((i << 5) + u0) * 8] = p0.v;
    *(uint4*)&At[((i << 5) + u1) * 8] = p1.v;
  }
  __syncthreads();

  // ---- phase 2: GEMM K=256 (A from swizzled LDS rows wq*16+l16) ----
  const unsigned short* Wb0 = Wt + (size_t)lane * 8;
  const int arow = wq * 16 + l16;
  f32x4 acc[4][4];
#pragma unroll
  for (int cb = 0; cb < 4; ++cb)
#pragma unroll
    for (int nb = 0; nb < 4; ++nb) acc[cb][nb] = (f32x4){0.f, 0.f, 0.f, 0.f};

#pragma unroll
  for (int cb = 0; cb < 4; ++cb) {
#pragma unroll
    for (int k0 = 0; k0 < 256; k0 += 32) {
      const int u = (k0 >> 3) + quad;
      bf16x8 a = *(const bf16x8*)&At[((arow << 5) + (u ^ (l16 & 7))) * 8];
#pragma unroll
      for (int nb = 0; nb < 4; ++nb) {
        bf16x8 b = *(const bf16x8*)(Wb0 +
            (((size_t)(cb * 4 + nb) * KS + (k0 >> 5)) << 9));
        acc[cb][nb] = __builtin_amdgcn_mfma_f32_16x16x32_bf16(a, b, acc[cb][nb], 0, 0, 0);
      }
    }
  }

  // ---- phase 3: in-register LN -> msgB ----
#pragma unroll
  for (int r = 0; r < 4; ++r) {
    float mean, inv;
    ln_reg(acc, r, mean, inv);
    const int row = R0 + wq * 16 + quad * 4 + r;
#pragma unroll
    for (int cb = 0; cb < 4; ++cb)
#pragma unroll
      for (int nb = 0; nb < 4; ++nb)
        msgB[(size_t)row * 256 + cb * 64 + nb * 16 + l16] =
            f2b((acc[cb][nb][r] - mean) * inv);
  }
}

// ---------------- split-S MFMA flash attention: partial (transposed) -------
// Head-major QKV: Q|K|V segments of kOff elems each; within a segment
// [head nh][token][64]. Grid: (L/256, NHt, split), 512 threads = 8 waves x
// 2 q-blocks x 16 queries. S^T = K Q^T; softmax in exp2 domain in-register
// (raw v_exp_f32); P^T stays in registers (Vt pcol permutation). K tile
// staged cooperatively into XOR-swizzled fragment-order LDS; V per-wave
// (pcol). O^T = V^T P. l-sum on the MATRIX pipe: ones-A MFMA over the P
// fragments gives the full 64-key denominator (no scalar adds, no final
// shuffles). setprio(1) around MFMA clusters. LDS = 34816 B.
__global__ __launch_bounds__(512, 4) void k_attn_p(float* __restrict__ pO,
                                                   float* __restrict__ pML,
                                                   const unsigned short* __restrict__ QKV,
                                                   unsigned long long kOff,
                                                   int L, int S, int chunk) {
  __shared__ __align__(16) char smem[34816];
  unsigned short* Kl = (unsigned short*)smem;                            // [2][4096]
  unsigned short (*Vt)[64][72] = (unsigned short (*)[64][72])(smem + 16384);
  const int tid = threadIdx.x;
  const int wq = tid >> 6, lane = tid & 63;                // wq 0..7
  const int l16 = lane & 15, quad = lane >> 4;
  const int q0 = blockIdx.x * 256;
  const int nh = blockIdx.y, NHt = gridDim.y;
  const int s0 = blockIdx.z * chunk;
  const float S2 = 0.18033688f;   // 0.125 * log2(e) — softmax in exp2 domain

  const unsigned short* Qh = QKV + (size_t)nh * L * 64;
  const unsigned short* Kh = QKV + kOff + (size_t)nh * S * 64;
  const unsigned short* Vh = QKV + 2 * kOff + (size_t)nh * S * 64;

  // Q fragments: 2 q-blocks per wave (rows q0 + (qb*8+wq)*16 + l16)
  bf16x8 qa[2][2];
#pragma unroll
  for (int qb = 0; qb < 2; ++qb) {
    const unsigned short* qp = Qh + (size_t)(q0 + (qb * 8 + wq) * 16 + l16) * 64;
    qa[qb][0] = *(const bf16x8*)(qp + quad * 8);
    qa[qb][1] = *(const bf16x8*)(qp + 32 + quad * 8);
  }

  // ones A-fragment for the l-sum MFMA (bf16 1.0 = 0x3F80)
  const short ONE = (short)0x3F80;
  const bf16x8 onesv = (bf16x8){ONE, ONE, ONE, ONE, ONE, ONE, ONE, ONE};

  f32x4 acc[2][4];   // O^T per q-block
  f32x4 lacc[2];     // denominator: all 4 elems equal Σ_key P[key][q=l16]
#pragma unroll
  for (int qb = 0; qb < 2; ++qb) {
#pragma unroll
    for (int i = 0; i < 4; ++i) acc[qb][i] = (f32x4){0.f, 0.f, 0.f, 0.f};
    lacc[qb] = (f32x4){0.f, 0.f, 0.f, 0.f};
  }
  float m_[2] = {-1e30f, -1e30f};   // log2 domain

  // K cooperative staging: thread -> (key = tid>>3, dh0 = (tid&7)*8).
  // Fragment-order LDS with XOR swizzle: slot ^= ((f&1)<<2)|(slot>>4), which
  // on the writer side equals tid&7 — makes both the b128 write phases and
  // the b128 read phases 2-lanes-per-bank-group (conflict-free).
  const int skey = tid >> 3;
  const int sdh0 = (tid & 7) * 8;
  const int kidx = (((skey >> 4) * 2 + (sdh0 >> 5)) * 64 +
                    (((sdh0 >> 3) & 3) * 16) + ((skey & 15) ^ (tid & 7))) * 8;
  // K read slots (logical slot = lane): phys = lane ^ ((c<<2)|quad)
  const int krd0 = lane ^ quad;
  const int krd1 = lane ^ (4 | quad);
  // V per-wave staging: lane = key, wave wq covers dh rows [wq*8, wq*8+8)
  const int vdh0 = wq * 8;
  // permuted Vt column (pcol): key -> 32*(kb>>1) + 8*q' + 4*(kb&1) + r so the
  // PV MFMA k-slots are each lane quad's own scores.
  const int pc = ((lane >> 5) << 5) + (((lane >> 2) & 3) << 3)
               + (((lane >> 4) & 1) << 2) + (lane & 3);

  uint4 kv = *(const uint4*)(Kh + (size_t)(s0 + skey) * 64 + sdh0);
  uint4 va = *(const uint4*)(Vh + (size_t)(s0 + lane) * 64 + vdh0);
  *(uint4*)&Kl[kidx] = kv;
  {
    const unsigned short* pv = (const unsigned short*)&va;
#pragma unroll
    for (int i = 0; i < 8; ++i) Vt[0][vdh0 + i][pc] = pv[i];
  }
  if (chunk > 64) {
    kv = *(const uint4*)(Kh + (size_t)(s0 + 64 + skey) * 64 + sdh0);
    va = *(const uint4*)(Vh + (size_t)(s0 + 64 + lane) * 64 + vdh0);
  }
  __syncthreads();

  int cur = 0;
  for (int t = 0; t < chunk; t += 64) {
    // S^T tile = K Q^T; kf from swizzled fragment-order LDS
    f32x4 sc[2][4];
    const unsigned short* Klc = Kl + cur * 4096;
    __builtin_amdgcn_s_setprio(1);
#pragma unroll
    for (int kb = 0; kb < 4; ++kb) {
      bf16x8 kf0 = *(const bf16x8*)&Klc[((kb * 2 + 0) * 64 + krd0) * 8];
      bf16x8 kf1 = *(const bf16x8*)&Klc[((kb * 2 + 1) * 64 + krd1) * 8];
#pragma unroll
      for (int qb = 0; qb < 2; ++qb) {
        f32x4 z = (f32x4){0.f, 0.f, 0.f, 0.f};
        z = __builtin_amdgcn_mfma_f32_16x16x32_bf16(kf0, qa[qb][0], z, 0, 0, 0);
        z = __builtin_amdgcn_mfma_f32_16x16x32_bf16(kf1, qa[qb][1], z, 0, 0, 0);
        sc[qb][kb] = z;
      }
    }
    __builtin_amdgcn_s_setprio(0);
    // stage tile t+64 into the other buffer; then issue loads for t+128
    if (t + 64 < chunk) {
      *(uint4*)&Kl[(cur ^ 1) * 4096 + kidx] = kv;
      const unsigned short* pv = (const unsigned short*)&va;
#pragma unroll
      for (int i = 0; i < 8; ++i) Vt[cur ^ 1][vdh0 + i][pc] = pv[i];
    }
    if (t + 128 < chunk) {
      kv = *(const uint4*)(Kh + (size_t)(s0 + t + 128 + skey) * 64 + sdh0);
      va = *(const uint4*)(Vh + (size_t)(s0 + t + 128 + lane) * 64 + vdh0);
    }
    // online softmax per q-block (exp2 domain, raw v_exp) + in-register P pack
    union { bf16x8 v; unsigned int w[4]; } ps0[2], ps1[2];
#pragma unroll
    for (int qb = 0; qb < 2; ++qb) {
      f32x4 mv01, mv;
#pragma unroll
      for (int r = 0; r < 4; ++r) mv01[r] = fmaxf(sc[qb][0][r], sc[qb][1][r]);
#pragma unroll
      for (int r = 0; r < 4; ++r) mv[r] = fmaxf(mv01[r], fmaxf(sc[qb][2][r], sc[qb][3][r]));
      float mx = fmaxf(fmaxf(mv[0], mv[1]), fmaxf(mv[2], mv[3])) * S2;
      mx = fmaxf(mx, __shfl_xor(mx, 16));
      mx = fmaxf(mx, __shfl_xor(mx, 32));
      float mn;
      if (__all(mx <= m_[qb] + 8.f)) {
        mn = m_[qb];                      // defer-max: P bounded by 2^8, no rescale
      } else {
        mn = fmaxf(m_[qb], mx);
        float alpha = fexp2(m_[qb] - mn);
        m_[qb] = mn;
#pragma unroll
        for (int r = 0; r < 4; ++r) lacc[qb][r] *= alpha;
#pragma unroll
        for (int nb = 0; nb < 4; ++nb)
#pragma unroll
          for (int r = 0; r < 4; ++r) acc[qb][nb][r] *= alpha;
      }
#pragma unroll
      for (int kb = 0; kb < 4; ++kb)
#pragma unroll
        for (int r = 0; r < 4; ++r)
          sc[qb][kb][r] = fexp2(fmaf(sc[qb][kb][r], S2, -mn));
      ps0[qb].w[0] = pk2(sc[qb][0][0], sc[qb][0][1]);
      ps0[qb].w[1] = pk2(sc[qb][0][2], sc[qb][0][3]);
      ps0[qb].w[2] = pk2(sc[qb][1][0], sc[qb][1][1]);
      ps0[qb].w[3] = pk2(sc[qb][1][2], sc[qb][1][3]);
      ps1[qb].w[0] = pk2(sc[qb][2][0], sc[qb][2][1]);
      ps1[qb].w[1] = pk2(sc[qb][2][2], sc[qb][2][3]);
      ps1[qb].w[2] = pk2(sc[qb][3][0], sc[qb][3][1]);
      ps1[qb].w[3] = pk2(sc[qb][3][2], sc[qb][3][3]);
    }
    // O^T += V^T P (Vt columns pcol-permuted; vb shared across q-blocks);
    // l-sum on the matrix pipe: ones-A MFMA over ps0/ps1 sums all 64 keys.
    __builtin_amdgcn_s_setprio(1);
#pragma unroll
    for (int db = 0; db < 4; ++db) {
      bf16x8 vb0 = *(const bf16x8*)&Vt[cur][db * 16 + l16][quad * 8];
      bf16x8 vb1 = *(const bf16x8*)&Vt[cur][db * 16 + l16][32 + quad * 8];
#pragma unroll
      for (int qb = 0; qb < 2; ++qb) {
        acc[qb][db] = __builtin_amdgcn_mfma_f32_16x16x32_bf16(vb0, ps0[qb].v, acc[qb][db], 0, 0, 0);
        acc[qb][db] = __builtin_amdgcn_mfma_f32_16x16x32_bf16(vb1, ps1[qb].v, acc[qb][db], 0, 0, 0);
      }
    }
#pragma unroll
    for (int qb = 0; qb < 2; ++qb) {
      lacc[qb] = __builtin_amdgcn_mfma_f32_16x16x32_bf16(onesv, ps0[qb].v, lacc[qb], 0, 0, 0);
      lacc[qb] = __builtin_amdgcn_mfma_f32_16x16x32_bf16(onesv, ps1[qb].v, lacc[qb], 0, 0, 0);
    }
    __builtin_amdgcn_s_setprio(0);
    __syncthreads();
    cur ^= 1;
  }

  // epilogue: transpose O^T -> O via LDS (reuse smem as f32 [64][68]);
  // 4 passes: qb x wave-half.
  float* Ot = (float*)smem;
#pragma unroll
  for (int qb = 0; qb < 2; ++qb) {
#pragma unroll
    for (int pass = 0; pass < 2; ++pass) {
      __syncthreads();
      if ((wq >> 2) == pass) {
#pragma unroll
        for (int db = 0; db < 4; ++db)
          *(f32x4*)&Ot[(size_t)((wq & 3) * 16 + l16) * 68 + db * 16 + quad * 4] = acc[qb][db];
      }
      __syncthreads();
      if ((wq >> 2) == pass) {
#pragma unroll
        for (int i = 0; i < 16; ++i) {
          const int row = q0 + (qb * 8 + wq) * 16 + i;
          pO[((size_t)(blockIdx.z * NHt + nh) * L + row) * 64 + lane] =
              Ot[(size_t)((wq & 3) * 16 + i) * 68 + lane];
        }
      }
    }
  }
  if (quad == 0) {
#pragma unroll
    for (int qb = 0; qb < 2; ++qb) {
      float* pml = pML + ((size_t)(blockIdx.z * NHt + nh) * L +
                          q0 + (qb * 8 + wq) * 16 + l16) * 2;
      pml[0] = m_[qb]; pml[1] = lacc[qb][0];
    }
  }
}

// ---------------- semantic gather, batched (index 2048 -> zeros) ------------
// 256 threads = 4 rows x 64; rows <8192 gather from src half with sIdx.
__global__ __launch_bounds__(256) void k_gather2(unsigned short* __restrict__ dst,
                                                 const float* __restrict__ sF,
                                                 const int* __restrict__ sIdx,
                                                 const int* __restrict__ tIdx) {
  const int row = blockIdx.x * 4 + (threadIdx.x >> 6);
  const int t = threadIdx.x & 63;
  const int half = row >> 13;
  const int r = row & 8191;
  const int g = r >> 9;
  const int b = g >> 3;               // mask_num = 8
  const int id = half ? tIdx[r] : sIdx[r];
  float4 v = {0.f, 0.f, 0.f, 0.f};
  if ((unsigned)id < 2048u) {
    const float* base = sF + (size_t)(half * 2 + b) * 524288;   // 2048*256
    v = ((const float4*)(base + (size_t)id * 256))[t];
  }
  ushort4 u; u.x = f2b(v.x); u.y = f2b(v.y); u.z = f2b(v.z); u.w = f2b(v.w);
  ((ushort4*)(dst + (size_t)row * 256))[t] = u;
}

// ---------------------------------------------------------------------------
extern "C" void kernel_launch(void* const* d_in, const int* in_sizes, int n_in,
                              void* d_out, int out_size, void* d_ws, size_t ws_size,
                              hipStream_t stream) {
  const void* src_feat = d_in[0];
  const void* tgt_feat = d_in[1];
  const int* s_sub = (const int*)d_in[6];
  const int* t_sub = (const int*)d_in[7];
  const void* src2d = d_in[11];
  const void* tgt2d = d_in[12];
  const void* dinoW = d_in[14];
  const void* qW = d_in[15];
  const void* kW = d_in[16];
  const void* vW = d_in[17];
  const void* mW = d_in[18];
  const void* w1 = d_in[19];
  const void* w2 = d_in[20];

  const int BIG = 1 << 30;
  char* p = (char*)d_ws;
  int* dflag = (int*)p;                       p += 256;
  float* sF = (float*)p;                      p += 4194304;   // [sF|tF] adjacent
  float* tF = (float*)p;                      p += 4194304;
  unsigned short* sB    = (unsigned short*)p; p += 2097152;   // [sB|tB] adjacent
  unsigned short* tB    = (unsigned short*)p; p += 2097152;
  unsigned short* s2B   = (unsigned short*)p; p += 2097152;   // [s2B|t2B] adjacent
  unsigned short* t2B   = (unsigned short*)p; p += 2097152;
  unsigned short* d2B   = (unsigned short*)p; p += 3145728;   // 4096x384 (reused)
  unsigned short* sSubB = (unsigned short*)p; p += 4194304;   // [sSub|tSub] adjacent
  unsigned short* tSubB = (unsigned short*)p; p += 4194304;
  // region A (25.2MB): qkvB (Q|K|V head-major) overlaid by msgB
  unsigned short* qkvB  = (unsigned short*)p;
  unsigned short* msgB  = (unsigned short*)(p + 8388608);     // A + 8.4MB  (8.4MB)
  p += 25165824;
  // region B (25.2MB): hB (16384x512)
  unsigned short* hB    = (unsigned short*)p;
  p += 25165824;
  unsigned short* WtD   = (unsigned short*)p; p += 196608;    // 256x384
  unsigned short* WtQKV = (unsigned short*)p; p += 1966080;   // 5x768x256
  unsigned short* WtM   = (unsigned short*)p; p += 655360;    // 5x256x256
  unsigned short* WtW1  = (unsigned short*)p; p += 2621440;   // 5x512x512
  unsigned short* WtW2  = (unsigned short*)p; p += 1310720;   // 5x256x512
  float* pO  = (float*)p;                     p += 33554432;  // split*NHt*L*64 f32
  float* pML = (float*)p;                     p += 2097152;
  // total ~121 MB

  // probe dtype (qW ~ N(0, 1/16))
  k_probe<<<1, 256, 0, stream>>>(dflag, (const unsigned short*)qW, 4096);

  // weight transposes + fragment pack; QKV packed per layer (768 rows = 48
  // nblks; q at 0, k at +65536, v at +131072 elements — the packed layout's
  // per-16-col chunk is 4096 elems so sub-block bases are unchanged).
  k_wt<<<dim3(8, 12, 1), 256, 0, stream>>>(WtD, dinoW, 384, 256, 0, dflag);
  k_wt<<<dim3(8, 8, 5), 256, 0, stream>>>(WtQKV,          qW, 256, 256, 196608, dflag);
  k_wt<<<dim3(8, 8, 5), 256, 0, stream>>>(WtQKV + 65536,  kW, 256, 256, 196608, dflag);
  k_wt<<<dim3(8, 8, 5), 256, 0, stream>>>(WtQKV + 131072, vW, 256, 256, 196608, dflag);
  k_wt<<<dim3(8, 8, 5), 256, 0, stream>>>(WtM, mW, 256, 256, 65536, dflag);
  k_wt<<<dim3(16, 16, 5), 256, 0, stream>>>(WtW1, w1, 512, 512, 262144, dflag);
  k_wt<<<dim3(8, 16, 5), 256, 0, stream>>>(WtW2, w2, 512, 256, 131072, dflag);

  // One attention block: QKV (single dispatch, row-XOR for KV, head-major
  // output), partial, fused combine+M-proj+LN, FFN-W1, fused W2+LN+residual.
  auto attnB = [&](int l, const unsigned short* Abase, int rowOff, int rowXor,
                   int M, int L, int S, int split, int NHt,
                   float* xF, unsigned short* xB, size_t outOff) {
    const int lg = (L == 2048) ? 11 : 9;
    k_gmm<256><<<dim3(12, M / 64), 256, 0, stream>>>(
        qkvB, 768, Abase, 256, Abase, 256, 256,
        WtQKV + (size_t)l * 196608, 0, rowOff, rowXor, 256, lg);
    const int chunk = S / split;
    k_attn_p<<<dim3(L / 256, NHt, split), 512, 0, stream>>>(
        pO, pML, qkvB, (unsigned long long)M * 256, L, S, chunk);
    // fused combine + M-proj + LN -> msgB (64-row wgs)
    k_mprojc<<<M / 64, 256, 0, stream>>>(msgB, pO, pML, lg, split, NHt,
                                         WtM + (size_t)l * 65536);
    // FFN W1 (relu) -> hB
    k_gmm<512><<<dim3(8, M / 64), 256, 0, stream>>>(
        hB, 512, xB, 256, msgB, 256, 256, WtW1 + (size_t)l * 262144, 1, 0, 0, BIG, 0);
    // fused W2 + LN + residual (64-row wgs)
    if (xF) k_gmm_ln<512><<<M / 64, 256, 0, stream>>>(
        xB, xF, nullptr, 0, nullptr, hB, 512, WtW2 + (size_t)l * 131072, 1, dflag);
    else    k_gmm_ln<512><<<M / 64, 256, 0, stream>>>(
        nullptr, nullptr, d_out, outOff, xB, hB, 512, WtW2 + (size_t)l * 131072, 2, dflag);
  };

  // ---- init ----
  k_load2<<<1024, 256, 0, stream>>>(sF, sB, src_feat, 262144, dflag);
  k_load2<<<1024, 256, 0, stream>>>(tF, tB, tgt_feat, 262144, dflag);
  k_loadb<<<1536, 256, 0, stream>>>(d2B, src2d, 393216, dflag);
  k_gmm<384><<<dim3(4, 64), 256, 0, stream>>>(s2B, 256, d2B, 384, d2B, 384, 384,
                                              WtD, 0, 0, 0, BIG, 0);
  k_loadb<<<1536, 256, 0, stream>>>(d2B, tgt2d, 393216, dflag);
  k_gmm<384><<<dim3(4, 64), 256, 0, stream>>>(t2B, 256, d2B, 384, d2B, 384, 384,
                                              WtD, 0, 0, 0, BIG, 0);

  // layer 0: self, src+tgt batched (M=8192, NHt=16)
  k_add_dino<<<2048, 256, 0, stream>>>(sF, sB, s2B, 524288);
  attnB(0, sB, 0, 0, 8192, 2048, 2048, 4, 16, sF, sB, 0);
  // layer 1: cross (sequential): Q rows from x, KV rows = x^4096
  attnB(1, sB, 0,    4096, 4096, 2048, 2048, 8, 8, sF, sB, 0);
  attnB(1, sB, 4096, 4096, 4096, 2048, 2048, 8, 8, tF, tB, 0);
  // layer 2: self batched (+dino)
  k_add_dino<<<2048, 256, 0, stream>>>(sF, sB, s2B, 524288);
  attnB(2, sB, 0, 0, 8192, 2048, 2048, 4, 16, sF, sB, 0);
  // layer 3: cross
  attnB(3, sB, 0,    4096, 4096, 2048, 2048, 8, 8, sF, sB, 0);
  attnB(3, sB, 4096, 4096, 4096, 2048, 2048, 8, 8, tF, tB, 0);
  // semantic gather (batched, pad index 2048 -> zeros)
  k_gather2<<<4096, 256, 0, stream>>>(sSubB, sF, s_sub, t_sub);
  // layer 4: semantic subspace cross, both directions batched (M=16384,
  // NHt=128, KV rows = rows ^ 8192 -> opposite subset)
  attnB(4, sSubB, 0, 8192, 16384, 512, 512, 2, 128, nullptr, sSubB, 2097152);

  // main outputs (sF|tF contiguous -> out[0..2097152))
  k_store<<<2048, 256, 0, stream>>>(d_out, 0, sF, 524288, dflag);
}

// Round 14
// 739.970 us; speedup vs baseline: 1.7028x; 1.7028x over previous
//
#include <hip/hip_runtime.h>
#include <hip/hip_bf16.h>
#include <cstdint>
#include <cstddef>

// ---------------------------------------------------------------------------
// SemanticTransformer forward. bf16 MFMA compute, f32 residual stream.
// Round 21: REVERT to r19 (measured best: 736.3 µs). r20's 64-row fused LN
// kernels starved the grid (M/64 = 128 wgs on 256 CUs -> 4.8% occupancy,
// 64 µs/dispatch); the 16-row versions keep 512-1024 wgs and measured best.
// Kernel set: fragment-packed weight GEMMs (k_gmm), fused combine+M-proj+LN
// (k_mprojc, 16-row), fused W2+LN+residual (k_gmm_ln, 16-row), attn_p with
// ones-MFMA l-sum + setprio + raw v_exp + swizzled K staging + defer-max,
// head-major QKV, XCD-chunked swizzles throughout.
// B=2, N=2048, C=256, NHEAD=4, DH=64, D2=384, G=16, Lp=512, layers=5
// ---------------------------------------------------------------------------

typedef __attribute__((ext_vector_type(8))) short bf16x8;   // 8 bf16, 4 VGPRs
typedef __attribute__((ext_vector_type(4))) float f32x4;

__device__ __forceinline__ float b2f(unsigned short u) {
  union { unsigned int i; float f; } v; v.i = ((unsigned int)u) << 16; return v.f;
}
__device__ __forceinline__ unsigned short f2b(float f) {
  __hip_bfloat16 h = __float2bfloat16(f);
  union { __hip_bfloat16 h; unsigned short u; } v; v.h = h; return v.u;
}
__device__ __forceinline__ unsigned int pk2(float a, float b) {
  return (unsigned int)f2b(a) | ((unsigned int)f2b(b) << 16);
}
// raw v_exp_f32 (2^x, 1 ULP) — no OCML denormal fixup
__device__ __forceinline__ float fexp2(float x) {
#if __has_builtin(__builtin_amdgcn_exp2f)
  return __builtin_amdgcn_exp2f(x);
#else
  float r; asm("v_exp_f32 %0, %1" : "=v"(r) : "v"(x)); return r;
#endif
}

// ---------------- dtype probe ----------------------------------------------
__global__ __launch_bounds__(256) void k_probe(int* __restrict__ flag,
                                               const unsigned short* __restrict__ w,
                                               int n) {
  __shared__ int ok[256];
  const int t = threadIdx.x;
  int good = 1;
  for (int i = t; i < n; i += 256) {
    float v = fabsf(b2f(w[i]));
    if (!(v < 1e3f)) good = 0;
  }
  ok[t] = good;
  __syncthreads();
  for (int s = 128; s; s >>= 1) {
    if (t < s) ok[t] &= ok[t + s];
    __syncthreads();
  }
  if (t == 0) *flag = ok[0];   // 1 = bf16 data, 0 = f32 data
}

// ---------------- input loads ----------------------------------------------
__global__ __launch_bounds__(256) void k_load2(float* __restrict__ dF,
                                               unsigned short* __restrict__ dB,
                                               const void* __restrict__ src,
                                               int n4, const int* __restrict__ flag) {
  int i = blockIdx.x * 256 + threadIdx.x;
  if (i >= n4) return;
  float4 f;
  if (*flag) {
    ushort4 u = ((const ushort4*)src)[i];
    f.x = b2f(u.x); f.y = b2f(u.y); f.z = b2f(u.z); f.w = b2f(u.w);
  } else {
    f = ((const float4*)src)[i];
  }
  ((float4*)dF)[i] = f;
  ushort4 o; o.x = f2b(f.x); o.y = f2b(f.y); o.z = f2b(f.z); o.w = f2b(f.w);
  ((ushort4*)dB)[i] = o;
}

__global__ __launch_bounds__(256) void k_loadb(unsigned short* __restrict__ dB,
                                               const void* __restrict__ src,
                                               int n4, const int* __restrict__ flag) {
  int i = blockIdx.x * 256 + threadIdx.x;
  if (i >= n4) return;
  if (*flag) {
    ((ushort4*)dB)[i] = ((const ushort4*)src)[i];
    return;
  }
  float4 f = ((const float4*)src)[i];
  ushort4 o; o.x = f2b(f.x); o.y = f2b(f.y); o.z = f2b(f.z); o.w = f2b(f.w);
  ((ushort4*)dB)[i] = o;
}

__global__ __launch_bounds__(256) void k_store(void* __restrict__ out, size_t off,
                                               const float* __restrict__ src,
                                               int n4, const int* __restrict__ flag) {
  int i = blockIdx.x * 256 + threadIdx.x;
  if (i >= n4) return;
  float4 f = ((const float4*)src)[i];
  if (*flag) {
    ushort4 u; u.x = f2b(f.x); u.y = f2b(f.y); u.z = f2b(f.z); u.w = f2b(f.w);
    ((ushort4*)((unsigned short*)out + off))[i] = u;
  } else {
    ((float4*)((float*)out + off))[i] = f;
  }
}

// dino residual: xF += addB; xB = bf16(xF)
__global__ __launch_bounds__(256) void k_add_dino(float* __restrict__ xF,
                                                  unsigned short* __restrict__ xB,
                                                  const unsigned short* __restrict__ addB,
                                                  int n4) {
  int i = blockIdx.x * 256 + threadIdx.x;
  if (i >= n4) return;
  float4 a = ((const float4*)xF)[i];
  ushort4 u = ((const ushort4*)addB)[i];
  a.x += b2f(u.x); a.y += b2f(u.y); a.z += b2f(u.z); a.w += b2f(u.w);
  ((float4*)xF)[i] = a;
  ushort4 o; o.x = f2b(a.x); o.y = f2b(a.y); o.z = f2b(a.z); o.w = f2b(a.w);
  ((ushort4*)xB)[i] = o;
}

// ---------------- weight transpose+cast+fragment-pack ----------------------
// Output layout (per z-slice): Wpk[nblk][kstep][lane][8] bf16, where
// nblk = n>>4, kstep = k>>5, lane = (kc>>3)*16 + (n&15), kc = k&31, e = kc&7.
// A wave's MFMA B-fragment (rows n0+nb*16+l16, cols k0+quad*8..+8) is then
// one contiguous 1KB block: ((nblk*KS + kstep)*64 + lane)*8.
__global__ __launch_bounds__(256) void k_wt(unsigned short* __restrict__ Wt,
                                            const void* __restrict__ W,
                                            int K, int N, int zStride,
                                            const int* __restrict__ flag) {
  __shared__ float tile[32][33];
  const int isbf = *flag;
  const int z = blockIdx.z;
  const unsigned short* Wb = (const unsigned short*)W + (size_t)z * K * N;
  const float* Wf = (const float*)W + (size_t)z * K * N;
  unsigned short* Wo = Wt + (size_t)z * zStride;
  const int KS = K >> 5;
  const int nx = blockIdx.x * 32, ky = blockIdx.y * 32;
  const int tx = threadIdx.x & 31, ty = threadIdx.x >> 5;  // ty 0..7
#pragma unroll
  for (int i = 0; i < 4; ++i) {
    int k = ky + ty + i * 8;
    float v = isbf ? b2f(Wb[(size_t)k * N + nx + tx]) : Wf[(size_t)k * N + nx + tx];
    tile[ty + i * 8][tx] = v;
  }
  __syncthreads();
  // element (k = ky+tx, n = nx+nn); ky multiple of 32 -> kstep = ky>>5, kc = tx
  const int kstep = ky >> 5;
  const int lanehi = (tx >> 3) << 4;   // quad*16
  const int e = tx & 7;
#pragma unroll
  for (int i = 0; i < 4; ++i) {
    int nn = ty + i * 8;
    int n_ = nx + nn;
    size_t idx = ((((size_t)(n_ >> 4) * KS + kstep) << 6) + (lanehi + (n_ & 15))) * 8 + e;
    Wo[idx] = f2b(tile[tx][nn]);
  }
}

// ---------------- MFMA GEMM, compile-time K --------------------------------
// Y[arow-relative output rows][n] = relu?( A[arow] @ Wpk ).
// arow = rowOff + row; for output columns n0 >= xorColStart, arow ^= rowXor.
// A concat on K: k<K1 from A1 else A2 (for W1 [x; msg]).
// B loads are contiguous 1KB fragment blocks (packed by k_wt); A/B register
// double-buffered; XCD-chunked wg swizzle for A-stripe L2 reuse.
// qkvLog2L != 0: head-major QKV epilogue — write to
// Y + sel*(M*256) + ((nbatch*4+h)*L + tok)*64 + dh, sel = n0>>8, h = (n0>>6)&3.
template<int KTOT>
__global__ __launch_bounds__(256, 4) void k_gmm(unsigned short* __restrict__ Y, int ldy,
                                                const unsigned short* __restrict__ A1, int lda1,
                                                const unsigned short* __restrict__ A2, int lda2,
                                                int K1,
                                                const unsigned short* __restrict__ Wt,
                                                int relu, int rowOff, int rowXor,
                                                int xorColStart, int qkvLog2L) {
  constexpr int KS = KTOT >> 5;
  const int tid = threadIdx.x;
  const int wq = tid >> 6, lane = tid & 63;
  const int l16 = lane & 15, quad = lane >> 4;
  // XCD-chunked swizzle (all grids have nwg % 8 == 0): contiguous work ids
  // stay on one XCD so column-blocks sharing an A-stripe hit the same L2.
  const int gx = gridDim.x;
  const int nwg = gx * gridDim.y;
  const int lid = blockIdx.y * gx + blockIdx.x;
  const int w = (lid & 7) * (nwg >> 3) + (lid >> 3);
  const int n0 = (w % gx) * 64, m0 = (w / gx) * 64;
  const int row = m0 + wq * 16 + l16;
  int arow = rowOff + row;
  if (n0 >= xorColStart) arow ^= rowXor;

  const unsigned short* Wb0 = Wt + ((size_t)(n0 >> 4) * KS << 6) * 8 + (size_t)lane * 8;

  f32x4 acc[4];
#pragma unroll
  for (int i = 0; i < 4; ++i) acc[i] = (f32x4){0.f, 0.f, 0.f, 0.f};

  auto ldA = [&](int k0) -> bf16x8 {
    const unsigned short* ap = (k0 < K1)
        ? (A1 + (size_t)arow * lda1 + k0)
        : (A2 + (size_t)arow * lda2 + (k0 - K1));
    return *(const bf16x8*)(ap + quad * 8);
  };
  auto ldB = [&](int k0, int nb) -> bf16x8 {
    return *(const bf16x8*)(Wb0 + ((size_t)nb * KS + (k0 >> 5)) * 512);
  };

  bf16x8 a0 = ldA(0), a1;
  bf16x8 b0[4], b1[4];
#pragma unroll
  for (int nb = 0; nb < 4; ++nb) b0[nb] = ldB(0, nb);

#pragma unroll
  for (int k0 = 0; k0 < KTOT; k0 += 64) {
    a1 = ldA(k0 + 32);
#pragma unroll
    for (int nb = 0; nb < 4; ++nb) b1[nb] = ldB(k0 + 32, nb);
#pragma unroll
    for (int nb = 0; nb < 4; ++nb)
      acc[nb] = __builtin_amdgcn_mfma_f32_16x16x32_bf16(a0, b0[nb], acc[nb], 0, 0, 0);
    if (k0 + 64 < KTOT) {
      a0 = ldA(k0 + 64);
#pragma unroll
      for (int nb = 0; nb < 4; ++nb) b0[nb] = ldB(k0 + 64, nb);
    }
#pragma unroll
    for (int nb = 0; nb < 4; ++nb)
      acc[nb] = __builtin_amdgcn_mfma_f32_16x16x32_bf16(a1, b1[nb], acc[nb], 0, 0, 0);
  }

  if (qkvLog2L) {
    const int Lm = (1 << qkvLog2L) - 1;
    const int sel = n0 >> 8;
    const int hh = (n0 >> 6) & 3;
    unsigned short* base = Y + (size_t)sel * ((size_t)gridDim.y << 14);  // M*256
#pragma unroll
    for (int r = 0; r < 4; ++r) {
      const int rr = m0 + wq * 16 + quad * 4 + r;
      const int tok = rr & Lm;
      const int hi = ((rr >> qkvLog2L) << 2) + hh;
      unsigned short* yp = base + ((((size_t)hi << qkvLog2L) + tok) << 6) + l16;
#pragma unroll
      for (int nb = 0; nb < 4; ++nb) yp[nb * 16] = f2b(acc[nb][r]);
    }
  } else {
#pragma unroll
    for (int r = 0; r < 4; ++r) {
      unsigned short* yp = Y + (size_t)(m0 + wq * 16 + quad * 4 + r) * ldy + n0;
#pragma unroll
      for (int nb = 0; nb < 4; ++nb) {
        float v = acc[nb][r];
        if (relu) v = fmaxf(v, 0.f);
        yp[nb * 16 + l16] = f2b(v);
      }
    }
  }
}

// ---------------- LayerNorm row stats (64-lane wave over 256 cols) ----------
__device__ __forceinline__ void row_stats(float4 v, float& mean, float& inv) {
  float s  = v.x + v.y + v.z + v.w;
  float s2 = fmaf(v.x, v.x, fmaf(v.y, v.y, fmaf(v.z, v.z, v.w * v.w)));
#pragma unroll
  for (int off = 32; off >= 1; off >>= 1) {
    s  += __shfl_xor(s,  off, 64);
    s2 += __shfl_xor(s2, off, 64);
  }
  mean = s * (1.f / 256.f);
  float var = s2 * (1.f / 256.f) - mean * mean;
  inv = rsqrtf(var + 1e-5f);
}

// ---------------- fused GEMM (N=256) + LayerNorm epilogue ------------------
// wg = 16 rows x 256 cols; 4 waves = 4 col-blocks; grid M/16 (1-D).
// Per-wave k-loop identical to k_gmm. Epilogue: acc -> LDS f32 [16][260],
// wave wq normalizes rows {wq, wq+4, wq+8, wq+12} with row_stats, then:
//   mode 1: xF[row] += norm; Yb[row] = bf16(xF[row])   (W2 + lnadd)
//   mode 2: r = b2f(xBres[row]) + norm -> out (+flag)  (W2 + lnadd_out)
template<int KTOT>
__global__ __launch_bounds__(256, 4) void k_gmm_ln(unsigned short* __restrict__ Yb,
                                                   float* __restrict__ xF,
                                                   void* __restrict__ outp, size_t outOff,
                                                   const unsigned short* __restrict__ xBres,
                                                   const unsigned short* __restrict__ A1,
                                                   int lda1,
                                                   const unsigned short* __restrict__ Wt,
                                                   int mode, const int* __restrict__ flag) {
  constexpr int KS = KTOT >> 5;
  __shared__ float Ot[16][260];
  const int tid = threadIdx.x;
  const int wq = tid >> 6, lane = tid & 63;
  const int l16 = lane & 15, quad = lane >> 4;
  const int nwg = gridDim.x;
  const int lid = blockIdx.x;
  const int w = (lid & 7) * (nwg >> 3) + (lid >> 3);
  const int R0 = w * 16;

  const unsigned short* Wb0 = Wt + ((size_t)(wq * 4) * KS << 6) * 8 + (size_t)lane * 8;
  const unsigned short* Ap = A1 + (size_t)(R0 + l16) * lda1;

  f32x4 acc[4];
#pragma unroll
  for (int i = 0; i < 4; ++i) acc[i] = (f32x4){0.f, 0.f, 0.f, 0.f};

  auto ldA = [&](int k0) -> bf16x8 { return *(const bf16x8*)(Ap + k0 + quad * 8); };
  auto ldB = [&](int k0, int nb) -> bf16x8 {
    return *(const bf16x8*)(Wb0 + ((size_t)nb * KS + (k0 >> 5)) * 512);
  };

  bf16x8 a0 = ldA(0), a1;
  bf16x8 b0[4], b1[4];
#pragma unroll
  for (int nb = 0; nb < 4; ++nb) b0[nb] = ldB(0, nb);

#pragma unroll
  for (int k0 = 0; k0 < KTOT; k0 += 64) {
    a1 = ldA(k0 + 32);
#pragma unroll
    for (int nb = 0; nb < 4; ++nb) b1[nb] = ldB(k0 + 32, nb);
#pragma unroll
    for (int nb = 0; nb < 4; ++nb)
      acc[nb] = __builtin_amdgcn_mfma_f32_16x16x32_bf16(a0, b0[nb], acc[nb], 0, 0, 0);
    if (k0 + 64 < KTOT) {
      a0 = ldA(k0 + 64);
#pragma unroll
      for (int nb = 0; nb < 4; ++nb) b0[nb] = ldB(k0 + 64, nb);
    }
#pragma unroll
    for (int nb = 0; nb < 4; ++nb)
      acc[nb] = __builtin_amdgcn_mfma_f32_16x16x32_bf16(a1, b1[nb], acc[nb], 0, 0, 0);
  }

  // epilogue: acc -> LDS (rows quad*4+r, cols wq*64+nb*16+l16)
#pragma unroll
  for (int nb = 0; nb < 4; ++nb)
#pragma unroll
    for (int r = 0; r < 4; ++r)
      Ot[quad * 4 + r][wq * 64 + nb * 16 + l16] = acc[nb][r];
  __syncthreads();

#pragma unroll
  for (int rr = 0; rr < 4; ++rr) {
    const int row = rr * 4 + wq;
    float4 v = *(const float4*)&Ot[row][lane * 4];
    float mean, inv; row_stats(v, mean, inv);
    float4 nv;
    nv.x = (v.x - mean) * inv; nv.y = (v.y - mean) * inv;
    nv.z = (v.z - mean) * inv; nv.w = (v.w - mean) * inv;
    const size_t gr = (size_t)(R0 + row) * 256 + lane * 4;
    if (mode == 1) {
      float4 xv = *(const float4*)(xF + gr);
      float4 rs;
      rs.x = xv.x + nv.x; rs.y = xv.y + nv.y; rs.z = xv.z + nv.z; rs.w = xv.w + nv.w;
      *(float4*)(xF + gr) = rs;
      ushort4 u; u.x = f2b(rs.x); u.y = f2b(rs.y); u.z = f2b(rs.z); u.w = f2b(rs.w);
      *(ushort4*)(Yb + gr) = u;
    } else {
      ushort4 xu = *(const ushort4*)(xBres + gr);
      float4 rs;
      rs.x = b2f(xu.x) + nv.x; rs.y = b2f(xu.y) + nv.y;
      rs.z = b2f(xu.z) + nv.z; rs.w = b2f(xu.w) + nv.w;
      if (*flag) {
        ushort4 u; u.x = f2b(rs.x); u.y = f2b(rs.y); u.z = f2b(rs.z); u.w = f2b(rs.w);
        *(ushort4*)((unsigned short*)outp + outOff + gr) = u;
      } else {
        *(float4*)((float*)outp + outOff + gr) = rs;
      }
    }
  }
}

// ---------------- fused attn-combine + M-proj GEMM + LN --------------------
// wg = 16 rows; phase 1: combine split partials for the 16 rows directly
// into an LDS A-tile (bf16, 16B-unit XOR swizzle u^(row&7) so the k-loop's
// b128 A-fragment reads are conflict-free); phase 2: K=256 GEMM with packed
// weights; phase 3: LN epilogue -> msgB. Replaces k_attn_c + M-proj.
__global__ __launch_bounds__(256, 4) void k_mprojc(unsigned short* __restrict__ msgB,
                                                   const float* __restrict__ pO,
                                                   const float* __restrict__ pML,
                                                   int lgL, int split, int NHt,
                                                   const unsigned short* __restrict__ Wt) {
  constexpr int KS = 8;   // K = 256
  __shared__ __align__(16) char smem[16640];
  unsigned short* At = (unsigned short*)smem;    // [16 rows][32 units][8 bf16]
  float (*Ot)[260] = (float (*)[260])smem;       // reused after barrier
  const int tid = threadIdx.x;
  const int wq = tid >> 6, lane = tid & 63;
  const int l16 = lane & 15, quad = lane >> 4;
  const int nwg = gridDim.x;
  const int lid = blockIdx.x;
  const int w = (lid & 7) * (nwg >> 3) + (lid >> 3);
  const int R0 = w * 16;
  const int L = 1 << lgL, Lm = L - 1;

  // ---- phase 1: combine -> At (each thread: one row, one 16-col chunk) ----
  {
    const int i = tid >> 4;          // row 0..15
    const int c = tid & 15;          // 16-col chunk; head h = c>>2
    const int gr = R0 + i;
    const int n = gr >> lgL;
    const int tok = gr & Lm;
    const int nh = n * 4 + (c >> 2);
    float M = -1e30f;
    for (int sp = 0; sp < split; ++sp)
      M = fmaxf(M, pML[(((size_t)sp * NHt + nh) * L + tok) * 2]);
    float4 a0 = {0,0,0,0}, a1 = {0,0,0,0}, a2 = {0,0,0,0}, a3 = {0,0,0,0};
    float lsum = 0.f;
    for (int sp = 0; sp < split; ++sp) {
      const float* pml = pML + (((size_t)sp * NHt + nh) * L + tok) * 2;
      float e = fexp2(pml[0] - M);
      lsum = fmaf(pml[1], e, lsum);
      const float4* po = (const float4*)(pO + (((size_t)sp * NHt + nh) * L + tok) * 64
                                         + (c & 3) * 16);
      float4 v0 = po[0], v1 = po[1], v2 = po[2], v3 = po[3];
      a0.x = fmaf(v0.x, e, a0.x); a0.y = fmaf(v0.y, e, a0.y);
      a0.z = fmaf(v0.z, e, a0.z); a0.w = fmaf(v0.w, e, a0.w);
      a1.x = fmaf(v1.x, e, a1.x); a1.y = fmaf(v1.y, e, a1.y);
      a1.z = fmaf(v1.z, e, a1.z); a1.w = fmaf(v1.w, e, a1.w);
      a2.x = fmaf(v2.x, e, a2.x); a2.y = fmaf(v2.y, e, a2.y);
      a2.z = fmaf(v2.z, e, a2.z); a2.w = fmaf(v2.w, e, a2.w);
      a3.x = fmaf(v3.x, e, a3.x); a3.y = fmaf(v3.y, e, a3.y);
      a3.z = fmaf(v3.z, e, a3.z); a3.w = fmaf(v3.w, e, a3.w);
    }
    float inv = 1.0f / lsum;
    union { unsigned short us[8]; uint4 v; } p0, p1;
    p0.us[0] = f2b(a0.x * inv); p0.us[1] = f2b(a0.y * inv);
    p0.us[2] = f2b(a0.z * inv); p0.us[3] = f2b(a0.w * inv);
    p0.us[4] = f2b(a1.x * inv); p0.us[5] = f2b(a1.y * inv);
    p0.us[6] = f2b(a1.z * inv); p0.us[7] = f2b(a1.w * inv);
    p1.us[0] = f2b(a2.x * inv); p1.us[1] = f2b(a2.y * inv);
    p1.us[2] = f2b(a2.z * inv); p1.us[3] = f2b(a2.w * inv);
    p1.us[4] = f2b(a3.x * inv); p1.us[5] = f2b(a3.y * inv);
    p1.us[6] = f2b(a3.z * inv); p1.us[7] = f2b(a3.w * inv);
    const int u0 = (2 * c) ^ (i & 7);
    const int u1 = (2 * c + 1) ^ (i & 7);
    *(uint4*)&At[((i << 5) + u0) * 8] = p0.v;
    *(uint4*)&At[((i << 5) + u1) * 8] = p1.v;
  }
  __syncthreads();

  // ---- phase 2: GEMM K=256, A from swizzled LDS, B from packed weights ----
  const unsigned short* Wb0 = Wt + ((size_t)(wq * 4) * KS << 6) * 8 + (size_t)lane * 8;
  f32x4 acc[4];
#pragma unroll
  for (int i = 0; i < 4; ++i) acc[i] = (f32x4){0.f, 0.f, 0.f, 0.f};

  auto ldA = [&](int k0) -> bf16x8 {
    const int u = (k0 >> 3) + quad;
    return *(const bf16x8*)&At[((l16 << 5) + (u ^ (l16 & 7))) * 8];
  };
  auto ldB = [&](int k0, int nb) -> bf16x8 {
    return *(const bf16x8*)(Wb0 + ((size_t)nb * KS + (k0 >> 5)) * 512);
  };

  bf16x8 b0[4], b1[4];
#pragma unroll
  for (int nb = 0; nb < 4; ++nb) b0[nb] = ldB(0, nb);
#pragma unroll
  for (int k0 = 0; k0 < 256; k0 += 64) {
#pragma unroll
    for (int nb = 0; nb < 4; ++nb) b1[nb] = ldB(k0 + 32, nb);
    bf16x8 a0 = ldA(k0);
#pragma unroll
    for (int nb = 0; nb < 4; ++nb)
      acc[nb] = __builtin_amdgcn_mfma_f32_16x16x32_bf16(a0, b0[nb], acc[nb], 0, 0, 0);
    if (k0 + 64 < 256) {
#pragma unroll
      for (int nb = 0; nb < 4; ++nb) b0[nb] = ldB(k0 + 64, nb);
    }
    bf16x8 a1 = ldA(k0 + 32);
#pragma unroll
    for (int nb = 0; nb < 4; ++nb)
      acc[nb] = __builtin_amdgcn_mfma_f32_16x16x32_bf16(a1, b1[nb], acc[nb], 0, 0, 0);
  }
  __syncthreads();   // all At reads done before Ot overwrite

  // ---- phase 3: LN epilogue -> msgB ----
#pragma unroll
  for (int nb = 0; nb < 4; ++nb)
#pragma unroll
    for (int r = 0; r < 4; ++r)
      Ot[quad * 4 + r][wq * 64 + nb * 16 + l16] = acc[nb][r];
  __syncthreads();

#pragma unroll
  for (int rr = 0; rr < 4; ++rr) {
    const int row = rr * 4 + wq;
    float4 v = *(const float4*)&Ot[row][lane * 4];
    float mean, inv; row_stats(v, mean, inv);
    ushort4 u;
    u.x = f2b((v.x - mean) * inv); u.y = f2b((v.y - mean) * inv);
    u.z = f2b((v.z - mean) * inv); u.w = f2b((v.w - mean) * inv);
    *(ushort4*)(msgB + (size_t)(R0 + row) * 256 + lane * 4) = u;
  }
}

// ---------------- split-S MFMA flash attention: partial (transposed) -------
// Head-major QKV: Q|K|V segments of kOff elems each; within a segment
// [head nh][token][64]. Grid: (L/256, NHt, split), 512 threads = 8 waves x
// 2 q-blocks x 16 queries. S^T = K Q^T; softmax in exp2 domain in-register
// (raw v_exp_f32); P^T stays in registers (Vt pcol permutation). K tile
// staged cooperatively into XOR-swizzled fragment-order LDS; V per-wave
// (pcol). O^T = V^T P. l-sum on the MATRIX pipe: ones-A MFMA over the P
// fragments gives the full 64-key denominator (no scalar adds, no final
// shuffles). setprio(1) around MFMA clusters. LDS = 34816 B.
__global__ __launch_bounds__(512, 4) void k_attn_p(float* __restrict__ pO,
                                                   float* __restrict__ pML,
                                                   const unsigned short* __restrict__ QKV,
                                                   unsigned long long kOff,
                                                   int L, int S, int chunk) {
  __shared__ __align__(16) char smem[34816];
  unsigned short* Kl = (unsigned short*)smem;                            // [2][4096]
  unsigned short (*Vt)[64][72] = (unsigned short (*)[64][72])(smem + 16384);
  const int tid = threadIdx.x;
  const int wq = tid >> 6, lane = tid & 63;                // wq 0..7
  const int l16 = lane & 15, quad = lane >> 4;
  const int q0 = blockIdx.x * 256;
  const int nh = blockIdx.y, NHt = gridDim.y;
  const int s0 = blockIdx.z * chunk;
  const float S2 = 0.18033688f;   // 0.125 * log2(e) — softmax in exp2 domain

  const unsigned short* Qh = QKV + (size_t)nh * L * 64;
  const unsigned short* Kh = QKV + kOff + (size_t)nh * S * 64;
  const unsigned short* Vh = QKV + 2 * kOff + (size_t)nh * S * 64;

  // Q fragments: 2 q-blocks per wave (rows q0 + (qb*8+wq)*16 + l16)
  bf16x8 qa[2][2];
#pragma unroll
  for (int qb = 0; qb < 2; ++qb) {
    const unsigned short* qp = Qh + (size_t)(q0 + (qb * 8 + wq) * 16 + l16) * 64;
    qa[qb][0] = *(const bf16x8*)(qp + quad * 8);
    qa[qb][1] = *(const bf16x8*)(qp + 32 + quad * 8);
  }

  // ones A-fragment for the l-sum MFMA (bf16 1.0 = 0x3F80)
  const short ONE = (short)0x3F80;
  const bf16x8 onesv = (bf16x8){ONE, ONE, ONE, ONE, ONE, ONE, ONE, ONE};

  f32x4 acc[2][4];   // O^T per q-block
  f32x4 lacc[2];     // denominator: all 4 elems equal Σ_key P[key][q=l16]
#pragma unroll
  for (int qb = 0; qb < 2; ++qb) {
#pragma unroll
    for (int i = 0; i < 4; ++i) acc[qb][i] = (f32x4){0.f, 0.f, 0.f, 0.f};
    lacc[qb] = (f32x4){0.f, 0.f, 0.f, 0.f};
  }
  float m_[2] = {-1e30f, -1e30f};   // log2 domain

  // K cooperative staging: thread -> (key = tid>>3, dh0 = (tid&7)*8).
  // Fragment-order LDS with XOR swizzle: slot ^= ((f&1)<<2)|(slot>>4), which
  // on the writer side equals tid&7 — makes both the b128 write phases and
  // the b128 read phases 2-lanes-per-bank-group (conflict-free).
  const int skey = tid >> 3;
  const int sdh0 = (tid & 7) * 8;
  const int kidx = (((skey >> 4) * 2 + (sdh0 >> 5)) * 64 +
                    (((sdh0 >> 3) & 3) * 16) + ((skey & 15) ^ (tid & 7))) * 8;
  // K read slots (logical slot = lane): phys = lane ^ ((c<<2)|quad)
  const int krd0 = lane ^ quad;
  const int krd1 = lane ^ (4 | quad);
  // V per-wave staging: lane = key, wave wq covers dh rows [wq*8, wq*8+8)
  const int vdh0 = wq * 8;
  // permuted Vt column (pcol): key -> 32*(kb>>1) + 8*q' + 4*(kb&1) + r so the
  // PV MFMA k-slots are each lane quad's own scores.
  const int pc = ((lane >> 5) << 5) + (((lane >> 2) & 3) << 3)
               + (((lane >> 4) & 1) << 2) + (lane & 3);

  uint4 kv = *(const uint4*)(Kh + (size_t)(s0 + skey) * 64 + sdh0);
  uint4 va = *(const uint4*)(Vh + (size_t)(s0 + lane) * 64 + vdh0);
  *(uint4*)&Kl[kidx] = kv;
  {
    const unsigned short* pv = (const unsigned short*)&va;
#pragma unroll
    for (int i = 0; i < 8; ++i) Vt[0][vdh0 + i][pc] = pv[i];
  }
  if (chunk > 64) {
    kv = *(const uint4*)(Kh + (size_t)(s0 + 64 + skey) * 64 + sdh0);
    va = *(const uint4*)(Vh + (size_t)(s0 + 64 + lane) * 64 + vdh0);
  }
  __syncthreads();

  int cur = 0;
  for (int t = 0; t < chunk; t += 64) {
    // S^T tile = K Q^T; kf from swizzled fragment-order LDS
    f32x4 sc[2][4];
    const unsigned short* Klc = Kl + cur * 4096;
    __builtin_amdgcn_s_setprio(1);
#pragma unroll
    for (int kb = 0; kb < 4; ++kb) {
      bf16x8 kf0 = *(const bf16x8*)&Klc[((kb * 2 + 0) * 64 + krd0) * 8];
      bf16x8 kf1 = *(const bf16x8*)&Klc[((kb * 2 + 1) * 64 + krd1) * 8];
#pragma unroll
      for (int qb = 0; qb < 2; ++qb) {
        f32x4 z = (f32x4){0.f, 0.f, 0.f, 0.f};
        z = __builtin_amdgcn_mfma_f32_16x16x32_bf16(kf0, qa[qb][0], z, 0, 0, 0);
        z = __builtin_amdgcn_mfma_f32_16x16x32_bf16(kf1, qa[qb][1], z, 0, 0, 0);
        sc[qb][kb] = z;
      }
    }
    __builtin_amdgcn_s_setprio(0);
    // stage tile t+64 into the other buffer; then issue loads for t+128
    if (t + 64 < chunk) {
      *(uint4*)&Kl[(cur ^ 1) * 4096 + kidx] = kv;
      const unsigned short* pv = (const unsigned short*)&va;
#pragma unroll
      for (int i = 0; i < 8; ++i) Vt[cur ^ 1][vdh0 + i][pc] = pv[i];
    }
    if (t + 128 < chunk) {
      kv = *(const uint4*)(Kh + (size_t)(s0 + t + 128 + skey) * 64 + sdh0);
      va = *(const uint4*)(Vh + (size_t)(s0 + t + 128 + lane) * 64 + vdh0);
    }
    // online softmax per q-block (exp2 domain, raw v_exp) + in-register P pack
    union { bf16x8 v; unsigned int w[4]; } ps0[2], ps1[2];
#pragma unroll
    for (int qb = 0; qb < 2; ++qb) {
      f32x4 mv01, mv;
#pragma unroll
      for (int r = 0; r < 4; ++r) mv01[r] = fmaxf(sc[qb][0][r], sc[qb][1][r]);
#pragma unroll
      for (int r = 0; r < 4; ++r) mv[r] = fmaxf(mv01[r], fmaxf(sc[qb][2][r], sc[qb][3][r]));
      float mx = fmaxf(fmaxf(mv[0], mv[1]), fmaxf(mv[2], mv[3])) * S2;
      mx = fmaxf(mx, __shfl_xor(mx, 16));
      mx = fmaxf(mx, __shfl_xor(mx, 32));
      float mn;
      if (__all(mx <= m_[qb] + 8.f)) {
        mn = m_[qb];                      // defer-max: P bounded by 2^8, no rescale
      } else {
        mn = fmaxf(m_[qb], mx);
        float alpha = fexp2(m_[qb] - mn);
        m_[qb] = mn;
#pragma unroll
        for (int r = 0; r < 4; ++r) lacc[qb][r] *= alpha;
#pragma unroll
        for (int nb = 0; nb < 4; ++nb)
#pragma unroll
          for (int r = 0; r < 4; ++r) acc[qb][nb][r] *= alpha;
      }
#pragma unroll
      for (int kb = 0; kb < 4; ++kb)
#pragma unroll
        for (int r = 0; r < 4; ++r)
          sc[qb][kb][r] = fexp2(fmaf(sc[qb][kb][r], S2, -mn));
      ps0[qb].w[0] = pk2(sc[qb][0][0], sc[qb][0][1]);
      ps0[qb].w[1] = pk2(sc[qb][0][2], sc[qb][0][3]);
      ps0[qb].w[2] = pk2(sc[qb][1][0], sc[qb][1][1]);
      ps0[qb].w[3] = pk2(sc[qb][1][2], sc[qb][1][3]);
      ps1[qb].w[0] = pk2(sc[qb][2][0], sc[qb][2][1]);
      ps1[qb].w[1] = pk2(sc[qb][2][2], sc[qb][2][3]);
      ps1[qb].w[2] = pk2(sc[qb][3][0], sc[qb][3][1]);
      ps1[qb].w[3] = pk2(sc[qb][3][2], sc[qb][3][3]);
    }
    // O^T += V^T P (Vt columns pcol-permuted; vb shared across q-blocks);
    // l-sum on the matrix pipe: ones-A MFMA over ps0/ps1 sums all 64 keys.
    __builtin_amdgcn_s_setprio(1);
#pragma unroll
    for (int db = 0; db < 4; ++db) {
      bf16x8 vb0 = *(const bf16x8*)&Vt[cur][db * 16 + l16][quad * 8];
      bf16x8 vb1 = *(const bf16x8*)&Vt[cur][db * 16 + l16][32 + quad * 8];
#pragma unroll
      for (int qb = 0; qb < 2; ++qb) {
        acc[qb][db] = __builtin_amdgcn_mfma_f32_16x16x32_bf16(vb0, ps0[qb].v, acc[qb][db], 0, 0, 0);
        acc[qb][db] = __builtin_amdgcn_mfma_f32_16x16x32_bf16(vb1, ps1[qb].v, acc[qb][db], 0, 0, 0);
      }
    }
#pragma unroll
    for (int qb = 0; qb < 2; ++qb) {
      lacc[qb] = __builtin_amdgcn_mfma_f32_16x16x32_bf16(onesv, ps0[qb].v, lacc[qb], 0, 0, 0);
      lacc[qb] = __builtin_amdgcn_mfma_f32_16x16x32_bf16(onesv, ps1[qb].v, lacc[qb], 0, 0, 0);
    }
    __builtin_amdgcn_s_setprio(0);
    __syncthreads();
    cur ^= 1;
  }

  // epilogue: transpose O^T -> O via LDS (reuse smem as f32 [64][68]);
  // 4 passes: qb x wave-half.
  float* Ot = (float*)smem;
#pragma unroll
  for (int qb = 0; qb < 2; ++qb) {
#pragma unroll
    for (int pass = 0; pass < 2; ++pass) {
      __syncthreads();
      if ((wq >> 2) == pass) {
#pragma unroll
        for (int db = 0; db < 4; ++db)
          *(f32x4*)&Ot[(size_t)((wq & 3) * 16 + l16) * 68 + db * 16 + quad * 4] = acc[qb][db];
      }
      __syncthreads();
      if ((wq >> 2) == pass) {
#pragma unroll
        for (int i = 0; i < 16; ++i) {
          const int row = q0 + (qb * 8 + wq) * 16 + i;
          pO[((size_t)(blockIdx.z * NHt + nh) * L + row) * 64 + lane] =
              Ot[(size_t)((wq & 3) * 16 + i) * 68 + lane];
        }
      }
    }
  }
  if (quad == 0) {
#pragma unroll
    for (int qb = 0; qb < 2; ++qb) {
      float* pml = pML + ((size_t)(blockIdx.z * NHt + nh) * L +
                          q0 + (qb * 8 + wq) * 16 + l16) * 2;
      pml[0] = m_[qb]; pml[1] = lacc[qb][0];
    }
  }
}

// ---------------- semantic gather, batched (index 2048 -> zeros) ------------
// 256 threads = 4 rows x 64; rows <8192 gather from src half with sIdx.
__global__ __launch_bounds__(256) void k_gather2(unsigned short* __restrict__ dst,
                                                 const float* __restrict__ sF,
                                                 const int* __restrict__ sIdx,
                                                 const int* __restrict__ tIdx) {
  const int row = blockIdx.x * 4 + (threadIdx.x >> 6);
  const int t = threadIdx.x & 63;
  const int half = row >> 13;
  const int r = row & 8191;
  const int g = r >> 9;
  const int b = g >> 3;               // mask_num = 8
  const int id = half ? tIdx[r] : sIdx[r];
  float4 v = {0.f, 0.f, 0.f, 0.f};
  if ((unsigned)id < 2048u) {
    const float* base = sF + (size_t)(half * 2 + b) * 524288;   // 2048*256
    v = ((const float4*)(base + (size_t)id * 256))[t];
  }
  ushort4 u; u.x = f2b(v.x); u.y = f2b(v.y); u.z = f2b(v.z); u.w = f2b(v.w);
  ((ushort4*)(dst + (size_t)row * 256))[t] = u;
}

// ---------------------------------------------------------------------------
extern "C" void kernel_launch(void* const* d_in, const int* in_sizes, int n_in,
                              void* d_out, int out_size, void* d_ws, size_t ws_size,
                              hipStream_t stream) {
  const void* src_feat = d_in[0];
  const void* tgt_feat = d_in[1];
  const int* s_sub = (const int*)d_in[6];
  const int* t_sub = (const int*)d_in[7];
  const void* src2d = d_in[11];
  const void* tgt2d = d_in[12];
  const void* dinoW = d_in[14];
  const void* qW = d_in[15];
  const void* kW = d_in[16];
  const void* vW = d_in[17];
  const void* mW = d_in[18];
  const void* w1 = d_in[19];
  const void* w2 = d_in[20];

  const int BIG = 1 << 30;
  char* p = (char*)d_ws;
  int* dflag = (int*)p;                       p += 256;
  float* sF = (float*)p;                      p += 4194304;   // [sF|tF] adjacent
  float* tF = (float*)p;                      p += 4194304;
  unsigned short* sB    = (unsigned short*)p; p += 2097152;   // [sB|tB] adjacent
  unsigned short* tB    = (unsigned short*)p; p += 2097152;
  unsigned short* s2B   = (unsigned short*)p; p += 2097152;   // [s2B|t2B] adjacent
  unsigned short* t2B   = (unsigned short*)p; p += 2097152;
  unsigned short* d2B   = (unsigned short*)p; p += 3145728;   // 4096x384 (reused)
  unsigned short* sSubB = (unsigned short*)p; p += 4194304;   // [sSub|tSub] adjacent
  unsigned short* tSubB = (unsigned short*)p; p += 4194304;
  // region A (25.2MB): qkvB (Q|K|V head-major) overlaid by msgB
  unsigned short* qkvB  = (unsigned short*)p;
  unsigned short* msgB  = (unsigned short*)(p + 8388608);     // A + 8.4MB  (8.4MB)
  p += 25165824;
  // region B (25.2MB): hB (16384x512)
  unsigned short* hB    = (unsigned short*)p;
  p += 25165824;
  unsigned short* WtD   = (unsigned short*)p; p += 196608;    // 256x384
  unsigned short* WtQKV = (unsigned short*)p; p += 1966080;   // 5x768x256
  unsigned short* WtM   = (unsigned short*)p; p += 655360;    // 5x256x256
  unsigned short* WtW1  = (unsigned short*)p; p += 2621440;   // 5x512x512
  unsigned short* WtW2  = (unsigned short*)p; p += 1310720;   // 5x256x512
  float* pO  = (float*)p;                     p += 33554432;  // split*NHt*L*64 f32
  float* pML = (float*)p;                     p += 2097152;
  // total ~121 MB

  // probe dtype (qW ~ N(0, 1/16))
  k_probe<<<1, 256, 0, stream>>>(dflag, (const unsigned short*)qW, 4096);

  // weight transposes + fragment pack; QKV packed per layer (768 rows = 48
  // nblks; q at 0, k at +65536, v at +131072 elements — the packed layout's
  // per-16-col chunk is 4096 elems so sub-block bases are unchanged).
  k_wt<<<dim3(8, 12, 1), 256, 0, stream>>>(WtD, dinoW, 384, 256, 0, dflag);
  k_wt<<<dim3(8, 8, 5), 256, 0, stream>>>(WtQKV,          qW, 256, 256, 196608, dflag);
  k_wt<<<dim3(8, 8, 5), 256, 0, stream>>>(WtQKV + 65536,  kW, 256, 256, 196608, dflag);
  k_wt<<<dim3(8, 8, 5), 256, 0, stream>>>(WtQKV + 131072, vW, 256, 256, 196608, dflag);
  k_wt<<<dim3(8, 8, 5), 256, 0, stream>>>(WtM, mW, 256, 256, 65536, dflag);
  k_wt<<<dim3(16, 16, 5), 256, 0, stream>>>(WtW1, w1, 512, 512, 262144, dflag);
  k_wt<<<dim3(8, 16, 5), 256, 0, stream>>>(WtW2, w2, 512, 256, 131072, dflag);

  // One attention block: QKV (single dispatch, row-XOR for KV, head-major
  // output), partial, fused combine+M-proj+LN, FFN-W1, fused W2+LN+residual.
  auto attnB = [&](int l, const unsigned short* Abase, int rowOff, int rowXor,
                   int M, int L, int S, int split, int NHt,
                   float* xF, unsigned short* xB, size_t outOff) {
    const int lg = (L == 2048) ? 11 : 9;
    k_gmm<256><<<dim3(12, M / 64), 256, 0, stream>>>(
        qkvB, 768, Abase, 256, Abase, 256, 256,
        WtQKV + (size_t)l * 196608, 0, rowOff, rowXor, 256, lg);
    const int chunk = S / split;
    k_attn_p<<<dim3(L / 256, NHt, split), 512, 0, stream>>>(
        pO, pML, qkvB, (unsigned long long)M * 256, L, S, chunk);
    // fused combine + M-proj + LN -> msgB
    k_mprojc<<<M / 16, 256, 0, stream>>>(msgB, pO, pML, lg, split, NHt,
                                         WtM + (size_t)l * 65536);
    // FFN W1 (relu) -> hB
    k_gmm<512><<<dim3(8, M / 64), 256, 0, stream>>>(
        hB, 512, xB, 256, msgB, 256, 256, WtW1 + (size_t)l * 262144, 1, 0, 0, BIG, 0);
    // fused W2 + LN + residual
    if (xF) k_gmm_ln<512><<<M / 16, 256, 0, stream>>>(
        xB, xF, nullptr, 0, nullptr, hB, 512, WtW2 + (size_t)l * 131072, 1, dflag);
    else    k_gmm_ln<512><<<M / 16, 256, 0, stream>>>(
        nullptr, nullptr, d_out, outOff, xB, hB, 512, WtW2 + (size_t)l * 131072, 2, dflag);
  };

  // ---- init ----
  k_load2<<<1024, 256, 0, stream>>>(sF, sB, src_feat, 262144, dflag);
  k_load2<<<1024, 256, 0, stream>>>(tF, tB, tgt_feat, 262144, dflag);
  k_loadb<<<1536, 256, 0, stream>>>(d2B, src2d, 393216, dflag);
  k_gmm<384><<<dim3(4, 64), 256, 0, stream>>>(s2B, 256, d2B, 384, d2B, 384, 384,
                                              WtD, 0, 0, 0, BIG, 0);
  k_loadb<<<1536, 256, 0, stream>>>(d2B, tgt2d, 393216, dflag);
  k_gmm<384><<<dim3(4, 64), 256, 0, stream>>>(t2B, 256, d2B, 384, d2B, 384, 384,
                                              WtD, 0, 0, 0, BIG, 0);

  // layer 0: self, src+tgt batched (M=8192, NHt=16)
  k_add_dino<<<2048, 256, 0, stream>>>(sF, sB, s2B, 524288);
  attnB(0, sB, 0, 0, 8192, 2048, 2048, 4, 16, sF, sB, 0);
  // layer 1: cross (sequential): Q rows from x, KV rows = x^4096
  attnB(1, sB, 0,    4096, 4096, 2048, 2048, 8, 8, sF, sB, 0);
  attnB(1, sB, 4096, 4096, 4096, 2048, 2048, 8, 8, tF, tB, 0);
  // layer 2: self batched (+dino)
  k_add_dino<<<2048, 256, 0, stream>>>(sF, sB, s2B, 524288);
  attnB(2, sB, 0, 0, 8192, 2048, 2048, 4, 16, sF, sB, 0);
  // layer 3: cross
  attnB(3, sB, 0,    4096, 4096, 2048, 2048, 8, 8, sF, sB, 0);
  attnB(3, sB, 4096, 4096, 4096, 2048, 2048, 8, 8, tF, tB, 0);
  // semantic gather (batched, pad index 2048 -> zeros)
  k_gather2<<<4096, 256, 0, stream>>>(sSubB, sF, s_sub, t_sub);
  // layer 4: semantic subspace cross, both directions batched (M=16384,
  // NHt=128, KV rows = rows ^ 8192 -> opposite subset)
  attnB(4, sSubB, 0, 8192, 16384, 512, 512, 2, 128, nullptr, sSubB, 2097152);

  // main outputs (sF|tF contiguous -> out[0..2097152))
  k_store<<<2048, 256, 0, stream>>>(d_out, 0, sF, 524288, dflag);
}

// Round 15
// 731.341 us; speedup vs baseline: 1.7229x; 1.0118x over previous
//
#include <hip/hip_runtime.h>
#include <hip/hip_bf16.h>
#include <cstdint>
#include <cstddef>

// ---------------------------------------------------------------------------
// SemanticTransformer forward. bf16 MFMA compute, f32 residual stream.
// Round 22: bf16 pO partials. The split-attention partial buffer was the
// largest counted HBM item left (33.5 MB write + 33.5 MB read per attn
// block x 7 = 470 MB = ~75 µs of BW time; attn_p WRITE_SIZE confirmed the
// writes reach HBM). The combine output is already bf16-rounded before the
// M-proj GEMM, so pre-rounding partials adds only a second ~0.4% relative
// rounding; m/l stay f32 in pML. attn_p epilogue stores f2b(O^T); k_mprojc
// combine loads bf16 and converts. Everything else identical to r21
// (measured best 736.3/740.0 µs): fragment-packed GEMMs, fused
// combine+M-proj+LN (16-row), fused W2+LN+residual (16-row), attn_p with
// ones-MFMA l-sum + setprio + raw v_exp + swizzled K staging + defer-max.
// B=2, N=2048, C=256, NHEAD=4, DH=64, D2=384, G=16, Lp=512, layers=5
// ---------------------------------------------------------------------------

typedef __attribute__((ext_vector_type(8))) short bf16x8;   // 8 bf16, 4 VGPRs
typedef __attribute__((ext_vector_type(4))) float f32x4;

__device__ __forceinline__ float b2f(unsigned short u) {
  union { unsigned int i; float f; } v; v.i = ((unsigned int)u) << 16; return v.f;
}
__device__ __forceinline__ unsigned short f2b(float f) {
  __hip_bfloat16 h = __float2bfloat16(f);
  union { __hip_bfloat16 h; unsigned short u; } v; v.h = h; return v.u;
}
__device__ __forceinline__ unsigned int pk2(float a, float b) {
  return (unsigned int)f2b(a) | ((unsigned int)f2b(b) << 16);
}
// raw v_exp_f32 (2^x, 1 ULP) — no OCML denormal fixup
__device__ __forceinline__ float fexp2(float x) {
#if __has_builtin(__builtin_amdgcn_exp2f)
  return __builtin_amdgcn_exp2f(x);
#else
  float r; asm("v_exp_f32 %0, %1" : "=v"(r) : "v"(x)); return r;
#endif
}

// ---------------- dtype probe ----------------------------------------------
__global__ __launch_bounds__(256) void k_probe(int* __restrict__ flag,
                                               const unsigned short* __restrict__ w,
                                               int n) {
  __shared__ int ok[256];
  const int t = threadIdx.x;
  int good = 1;
  for (int i = t; i < n; i += 256) {
    float v = fabsf(b2f(w[i]));
    if (!(v < 1e3f)) good = 0;
  }
  ok[t] = good;
  __syncthreads();
  for (int s = 128; s; s >>= 1) {
    if (t < s) ok[t] &= ok[t + s];
    __syncthreads();
  }
  if (t == 0) *flag = ok[0];   // 1 = bf16 data, 0 = f32 data
}

// ---------------- input loads ----------------------------------------------
__global__ __launch_bounds__(256) void k_load2(float* __restrict__ dF,
                                               unsigned short* __restrict__ dB,
                                               const void* __restrict__ src,
                                               int n4, const int* __restrict__ flag) {
  int i = blockIdx.x * 256 + threadIdx.x;
  if (i >= n4) return;
  float4 f;
  if (*flag) {
    ushort4 u = ((const ushort4*)src)[i];
    f.x = b2f(u.x); f.y = b2f(u.y); f.z = b2f(u.z); f.w = b2f(u.w);
  } else {
    f = ((const float4*)src)[i];
  }
  ((float4*)dF)[i] = f;
  ushort4 o; o.x = f2b(f.x); o.y = f2b(f.y); o.z = f2b(f.z); o.w = f2b(f.w);
  ((ushort4*)dB)[i] = o;
}

__global__ __launch_bounds__(256) void k_loadb(unsigned short* __restrict__ dB,
                                               const void* __restrict__ src,
                                               int n4, const int* __restrict__ flag) {
  int i = blockIdx.x * 256 + threadIdx.x;
  if (i >= n4) return;
  if (*flag) {
    ((ushort4*)dB)[i] = ((const ushort4*)src)[i];
    return;
  }
  float4 f = ((const float4*)src)[i];
  ushort4 o; o.x = f2b(f.x); o.y = f2b(f.y); o.z = f2b(f.z); o.w = f2b(f.w);
  ((ushort4*)dB)[i] = o;
}

__global__ __launch_bounds__(256) void k_store(void* __restrict__ out, size_t off,
                                               const float* __restrict__ src,
                                               int n4, const int* __restrict__ flag) {
  int i = blockIdx.x * 256 + threadIdx.x;
  if (i >= n4) return;
  float4 f = ((const float4*)src)[i];
  if (*flag) {
    ushort4 u; u.x = f2b(f.x); u.y = f2b(f.y); u.z = f2b(f.z); u.w = f2b(f.w);
    ((ushort4*)((unsigned short*)out + off))[i] = u;
  } else {
    ((float4*)((float*)out + off))[i] = f;
  }
}

// dino residual: xF += addB; xB = bf16(xF)
__global__ __launch_bounds__(256) void k_add_dino(float* __restrict__ xF,
                                                  unsigned short* __restrict__ xB,
                                                  const unsigned short* __restrict__ addB,
                                                  int n4) {
  int i = blockIdx.x * 256 + threadIdx.x;
  if (i >= n4) return;
  float4 a = ((const float4*)xF)[i];
  ushort4 u = ((const ushort4*)addB)[i];
  a.x += b2f(u.x); a.y += b2f(u.y); a.z += b2f(u.z); a.w += b2f(u.w);
  ((float4*)xF)[i] = a;
  ushort4 o; o.x = f2b(a.x); o.y = f2b(a.y); o.z = f2b(a.z); o.w = f2b(a.w);
  ((ushort4*)xB)[i] = o;
}

// ---------------- weight transpose+cast+fragment-pack ----------------------
// Output layout (per z-slice): Wpk[nblk][kstep][lane][8] bf16, where
// nblk = n>>4, kstep = k>>5, lane = (kc>>3)*16 + (n&15), kc = k&31, e = kc&7.
// A wave's MFMA B-fragment (rows n0+nb*16+l16, cols k0+quad*8..+8) is then
// one contiguous 1KB block: ((nblk*KS + kstep)*64 + lane)*8.
__global__ __launch_bounds__(256) void k_wt(unsigned short* __restrict__ Wt,
                                            const void* __restrict__ W,
                                            int K, int N, int zStride,
                                            const int* __restrict__ flag) {
  __shared__ float tile[32][33];
  const int isbf = *flag;
  const int z = blockIdx.z;
  const unsigned short* Wb = (const unsigned short*)W + (size_t)z * K * N;
  const float* Wf = (const float*)W + (size_t)z * K * N;
  unsigned short* Wo = Wt + (size_t)z * zStride;
  const int KS = K >> 5;
  const int nx = blockIdx.x * 32, ky = blockIdx.y * 32;
  const int tx = threadIdx.x & 31, ty = threadIdx.x >> 5;  // ty 0..7
#pragma unroll
  for (int i = 0; i < 4; ++i) {
    int k = ky + ty + i * 8;
    float v = isbf ? b2f(Wb[(size_t)k * N + nx + tx]) : Wf[(size_t)k * N + nx + tx];
    tile[ty + i * 8][tx] = v;
  }
  __syncthreads();
  // element (k = ky+tx, n = nx+nn); ky multiple of 32 -> kstep = ky>>5, kc = tx
  const int kstep = ky >> 5;
  const int lanehi = (tx >> 3) << 4;   // quad*16
  const int e = tx & 7;
#pragma unroll
  for (int i = 0; i < 4; ++i) {
    int nn = ty + i * 8;
    int n_ = nx + nn;
    size_t idx = ((((size_t)(n_ >> 4) * KS + kstep) << 6) + (lanehi + (n_ & 15))) * 8 + e;
    Wo[idx] = f2b(tile[tx][nn]);
  }
}

// ---------------- MFMA GEMM, compile-time K --------------------------------
// Y[arow-relative output rows][n] = relu?( A[arow] @ Wpk ).
// arow = rowOff + row; for output columns n0 >= xorColStart, arow ^= rowXor.
// A concat on K: k<K1 from A1 else A2 (for W1 [x; msg]).
// B loads are contiguous 1KB fragment blocks (packed by k_wt); A/B register
// double-buffered; XCD-chunked wg swizzle for A-stripe L2 reuse.
// qkvLog2L != 0: head-major QKV epilogue — write to
// Y + sel*(M*256) + ((nbatch*4+h)*L + tok)*64 + dh, sel = n0>>8, h = (n0>>6)&3.
template<int KTOT>
__global__ __launch_bounds__(256, 4) void k_gmm(unsigned short* __restrict__ Y, int ldy,
                                                const unsigned short* __restrict__ A1, int lda1,
                                                const unsigned short* __restrict__ A2, int lda2,
                                                int K1,
                                                const unsigned short* __restrict__ Wt,
                                                int relu, int rowOff, int rowXor,
                                                int xorColStart, int qkvLog2L) {
  constexpr int KS = KTOT >> 5;
  const int tid = threadIdx.x;
  const int wq = tid >> 6, lane = tid & 63;
  const int l16 = lane & 15, quad = lane >> 4;
  // XCD-chunked swizzle (all grids have nwg % 8 == 0): contiguous work ids
  // stay on one XCD so column-blocks sharing an A-stripe hit the same L2.
  const int gx = gridDim.x;
  const int nwg = gx * gridDim.y;
  const int lid = blockIdx.y * gx + blockIdx.x;
  const int w = (lid & 7) * (nwg >> 3) + (lid >> 3);
  const int n0 = (w % gx) * 64, m0 = (w / gx) * 64;
  const int row = m0 + wq * 16 + l16;
  int arow = rowOff + row;
  if (n0 >= xorColStart) arow ^= rowXor;

  const unsigned short* Wb0 = Wt + ((size_t)(n0 >> 4) * KS << 6) * 8 + (size_t)lane * 8;

  f32x4 acc[4];
#pragma unroll
  for (int i = 0; i < 4; ++i) acc[i] = (f32x4){0.f, 0.f, 0.f, 0.f};

  auto ldA = [&](int k0) -> bf16x8 {
    const unsigned short* ap = (k0 < K1)
        ? (A1 + (size_t)arow * lda1 + k0)
        : (A2 + (size_t)arow * lda2 + (k0 - K1));
    return *(const bf16x8*)(ap + quad * 8);
  };
  auto ldB = [&](int k0, int nb) -> bf16x8 {
    return *(const bf16x8*)(Wb0 + ((size_t)nb * KS + (k0 >> 5)) * 512);
  };

  bf16x8 a0 = ldA(0), a1;
  bf16x8 b0[4], b1[4];
#pragma unroll
  for (int nb = 0; nb < 4; ++nb) b0[nb] = ldB(0, nb);

#pragma unroll
  for (int k0 = 0; k0 < KTOT; k0 += 64) {
    a1 = ldA(k0 + 32);
#pragma unroll
    for (int nb = 0; nb < 4; ++nb) b1[nb] = ldB(k0 + 32, nb);
#pragma unroll
    for (int nb = 0; nb < 4; ++nb)
      acc[nb] = __builtin_amdgcn_mfma_f32_16x16x32_bf16(a0, b0[nb], acc[nb], 0, 0, 0);
    if (k0 + 64 < KTOT) {
      a0 = ldA(k0 + 64);
#pragma unroll
      for (int nb = 0; nb < 4; ++nb) b0[nb] = ldB(k0 + 64, nb);
    }
#pragma unroll
    for (int nb = 0; nb < 4; ++nb)
      acc[nb] = __builtin_amdgcn_mfma_f32_16x16x32_bf16(a1, b1[nb], acc[nb], 0, 0, 0);
  }

  if (qkvLog2L) {
    const int Lm = (1 << qkvLog2L) - 1;
    const int sel = n0 >> 8;
    const int hh = (n0 >> 6) & 3;
    unsigned short* base = Y + (size_t)sel * ((size_t)gridDim.y << 14);  // M*256
#pragma unroll
    for (int r = 0; r < 4; ++r) {
      const int rr = m0 + wq * 16 + quad * 4 + r;
      const int tok = rr & Lm;
      const int hi = ((rr >> qkvLog2L) << 2) + hh;
      unsigned short* yp = base + ((((size_t)hi << qkvLog2L) + tok) << 6) + l16;
#pragma unroll
      for (int nb = 0; nb < 4; ++nb) yp[nb * 16] = f2b(acc[nb][r]);
    }
  } else {
#pragma unroll
    for (int r = 0; r < 4; ++r) {
      unsigned short* yp = Y + (size_t)(m0 + wq * 16 + quad * 4 + r) * ldy + n0;
#pragma unroll
      for (int nb = 0; nb < 4; ++nb) {
        float v = acc[nb][r];
        if (relu) v = fmaxf(v, 0.f);
        yp[nb * 16 + l16] = f2b(v);
      }
    }
  }
}

// ---------------- LayerNorm row stats (64-lane wave over 256 cols) ----------
__device__ __forceinline__ void row_stats(float4 v, float& mean, float& inv) {
  float s  = v.x + v.y + v.z + v.w;
  float s2 = fmaf(v.x, v.x, fmaf(v.y, v.y, fmaf(v.z, v.z, v.w * v.w)));
#pragma unroll
  for (int off = 32; off >= 1; off >>= 1) {
    s  += __shfl_xor(s,  off, 64);
    s2 += __shfl_xor(s2, off, 64);
  }
  mean = s * (1.f / 256.f);
  float var = s2 * (1.f / 256.f) - mean * mean;
  inv = rsqrtf(var + 1e-5f);
}

// ---------------- fused GEMM (N=256) + LayerNorm epilogue ------------------
// wg = 16 rows x 256 cols; 4 waves = 4 col-blocks; grid M/16 (1-D).
// Per-wave k-loop identical to k_gmm. Epilogue: acc -> LDS f32 [16][260],
// wave wq normalizes rows {wq, wq+4, wq+8, wq+12} with row_stats, then:
//   mode 1: xF[row] += norm; Yb[row] = bf16(xF[row])   (W2 + lnadd)
//   mode 2: r = b2f(xBres[row]) + norm -> out (+flag)  (W2 + lnadd_out)
template<int KTOT>
__global__ __launch_bounds__(256, 4) void k_gmm_ln(unsigned short* __restrict__ Yb,
                                                   float* __restrict__ xF,
                                                   void* __restrict__ outp, size_t outOff,
                                                   const unsigned short* __restrict__ xBres,
                                                   const unsigned short* __restrict__ A1,
                                                   int lda1,
                                                   const unsigned short* __restrict__ Wt,
                                                   int mode, const int* __restrict__ flag) {
  constexpr int KS = KTOT >> 5;
  __shared__ float Ot[16][260];
  const int tid = threadIdx.x;
  const int wq = tid >> 6, lane = tid & 63;
  const int l16 = lane & 15, quad = lane >> 4;
  const int nwg = gridDim.x;
  const int lid = blockIdx.x;
  const int w = (lid & 7) * (nwg >> 3) + (lid >> 3);
  const int R0 = w * 16;

  const unsigned short* Wb0 = Wt + ((size_t)(wq * 4) * KS << 6) * 8 + (size_t)lane * 8;
  const unsigned short* Ap = A1 + (size_t)(R0 + l16) * lda1;

  f32x4 acc[4];
#pragma unroll
  for (int i = 0; i < 4; ++i) acc[i] = (f32x4){0.f, 0.f, 0.f, 0.f};

  auto ldA = [&](int k0) -> bf16x8 { return *(const bf16x8*)(Ap + k0 + quad * 8); };
  auto ldB = [&](int k0, int nb) -> bf16x8 {
    return *(const bf16x8*)(Wb0 + ((size_t)nb * KS + (k0 >> 5)) * 512);
  };

  bf16x8 a0 = ldA(0), a1;
  bf16x8 b0[4], b1[4];
#pragma unroll
  for (int nb = 0; nb < 4; ++nb) b0[nb] = ldB(0, nb);

#pragma unroll
  for (int k0 = 0; k0 < KTOT; k0 += 64) {
    a1 = ldA(k0 + 32);
#pragma unroll
    for (int nb = 0; nb < 4; ++nb) b1[nb] = ldB(k0 + 32, nb);
#pragma unroll
    for (int nb = 0; nb < 4; ++nb)
      acc[nb] = __builtin_amdgcn_mfma_f32_16x16x32_bf16(a0, b0[nb], acc[nb], 0, 0, 0);
    if (k0 + 64 < KTOT) {
      a0 = ldA(k0 + 64);
#pragma unroll
      for (int nb = 0; nb < 4; ++nb) b0[nb] = ldB(k0 + 64, nb);
    }
#pragma unroll
    for (int nb = 0; nb < 4; ++nb)
      acc[nb] = __builtin_amdgcn_mfma_f32_16x16x32_bf16(a1, b1[nb], acc[nb], 0, 0, 0);
  }

  // epilogue: acc -> LDS (rows quad*4+r, cols wq*64+nb*16+l16)
#pragma unroll
  for (int nb = 0; nb < 4; ++nb)
#pragma unroll
    for (int r = 0; r < 4; ++r)
      Ot[quad * 4 + r][wq * 64 + nb * 16 + l16] = acc[nb][r];
  __syncthreads();

#pragma unroll
  for (int rr = 0; rr < 4; ++rr) {
    const int row = rr * 4 + wq;
    float4 v = *(const float4*)&Ot[row][lane * 4];
    float mean, inv; row_stats(v, mean, inv);
    float4 nv;
    nv.x = (v.x - mean) * inv; nv.y = (v.y - mean) * inv;
    nv.z = (v.z - mean) * inv; nv.w = (v.w - mean) * inv;
    const size_t gr = (size_t)(R0 + row) * 256 + lane * 4;
    if (mode == 1) {
      float4 xv = *(const float4*)(xF + gr);
      float4 rs;
      rs.x = xv.x + nv.x; rs.y = xv.y + nv.y; rs.z = xv.z + nv.z; rs.w = xv.w + nv.w;
      *(float4*)(xF + gr) = rs;
      ushort4 u; u.x = f2b(rs.x); u.y = f2b(rs.y); u.z = f2b(rs.z); u.w = f2b(rs.w);
      *(ushort4*)(Yb + gr) = u;
    } else {
      ushort4 xu = *(const ushort4*)(xBres + gr);
      float4 rs;
      rs.x = b2f(xu.x) + nv.x; rs.y = b2f(xu.y) + nv.y;
      rs.z = b2f(xu.z) + nv.z; rs.w = b2f(xu.w) + nv.w;
      if (*flag) {
        ushort4 u; u.x = f2b(rs.x); u.y = f2b(rs.y); u.z = f2b(rs.z); u.w = f2b(rs.w);
        *(ushort4*)((unsigned short*)outp + outOff + gr) = u;
      } else {
        *(float4*)((float*)outp + outOff + gr) = rs;
      }
    }
  }
}

// ---------------- fused attn-combine + M-proj GEMM + LN --------------------
// wg = 16 rows; phase 1: combine bf16 split partials for the 16 rows into an
// LDS A-tile (bf16, 16B-unit XOR swizzle u^(row&7) so the k-loop's b128
// A-fragment reads are conflict-free); phase 2: K=256 GEMM with packed
// weights; phase 3: LN epilogue -> msgB. Replaces k_attn_c + M-proj.
__global__ __launch_bounds__(256, 4) void k_mprojc(unsigned short* __restrict__ msgB,
                                                   const unsigned short* __restrict__ pO,
                                                   const float* __restrict__ pML,
                                                   int lgL, int split, int NHt,
                                                   const unsigned short* __restrict__ Wt) {
  constexpr int KS = 8;   // K = 256
  __shared__ __align__(16) char smem[16640];
  unsigned short* At = (unsigned short*)smem;    // [16 rows][32 units][8 bf16]
  float (*Ot)[260] = (float (*)[260])smem;       // reused after barrier
  const int tid = threadIdx.x;
  const int wq = tid >> 6, lane = tid & 63;
  const int l16 = lane & 15, quad = lane >> 4;
  const int nwg = gridDim.x;
  const int lid = blockIdx.x;
  const int w = (lid & 7) * (nwg >> 3) + (lid >> 3);
  const int R0 = w * 16;
  const int L = 1 << lgL, Lm = L - 1;

  // ---- phase 1: combine -> At (each thread: one row, one 16-col chunk) ----
  {
    const int i = tid >> 4;          // row 0..15
    const int c = tid & 15;          // 16-col chunk; head h = c>>2
    const int gr = R0 + i;
    const int n = gr >> lgL;
    const int tok = gr & Lm;
    const int nh = n * 4 + (c >> 2);
    float M = -1e30f;
    for (int sp = 0; sp < split; ++sp)
      M = fmaxf(M, pML[(((size_t)sp * NHt + nh) * L + tok) * 2]);
    float av[16];
#pragma unroll
    for (int j = 0; j < 16; ++j) av[j] = 0.f;
    float lsum = 0.f;
    for (int sp = 0; sp < split; ++sp) {
      const float* pml = pML + (((size_t)sp * NHt + nh) * L + tok) * 2;
      float e = fexp2(pml[0] - M);
      lsum = fmaf(pml[1], e, lsum);
      const unsigned short* po = pO + (((size_t)sp * NHt + nh) * L + tok) * 64
                                 + (c & 3) * 16;
      uint4 raw0 = *(const uint4*)po;
      uint4 raw1 = *(const uint4*)(po + 8);
      const unsigned short* q0 = (const unsigned short*)&raw0;
      const unsigned short* q1 = (const unsigned short*)&raw1;
#pragma unroll
      for (int j = 0; j < 8; ++j) av[j]     = fmaf(b2f(q0[j]), e, av[j]);
#pragma unroll
      for (int j = 0; j < 8; ++j) av[8 + j] = fmaf(b2f(q1[j]), e, av[8 + j]);
    }
    float inv = 1.0f / lsum;
    union { unsigned short us[8]; uint4 v; } p0, p1;
#pragma unroll
    for (int j = 0; j < 8; ++j) p0.us[j] = f2b(av[j] * inv);
#pragma unroll
    for (int j = 0; j < 8; ++j) p1.us[j] = f2b(av[8 + j] * inv);
    const int u0 = (2 * c) ^ (i & 7);
    const int u1 = (2 * c + 1) ^ (i & 7);
    *(uint4*)&At[((i << 5) + u0) * 8] = p0.v;
    *(uint4*)&At[((i << 5) + u1) * 8] = p1.v;
  }
  __syncthreads();

  // ---- phase 2: GEMM K=256, A from swizzled LDS, B from packed weights ----
  const unsigned short* Wb0 = Wt + ((size_t)(wq * 4) * KS << 6) * 8 + (size_t)lane * 8;
  f32x4 acc[4];
#pragma unroll
  for (int i = 0; i < 4; ++i) acc[i] = (f32x4){0.f, 0.f, 0.f, 0.f};

  auto ldA = [&](int k0) -> bf16x8 {
    const int u = (k0 >> 3) + quad;
    return *(const bf16x8*)&At[((l16 << 5) + (u ^ (l16 & 7))) * 8];
  };
  auto ldB = [&](int k0, int nb) -> bf16x8 {
    return *(const bf16x8*)(Wb0 + ((size_t)nb * KS + (k0 >> 5)) * 512);
  };

  bf16x8 b0[4], b1[4];
#pragma unroll
  for (int nb = 0; nb < 4; ++nb) b0[nb] = ldB(0, nb);
#pragma unroll
  for (int k0 = 0; k0 < 256; k0 += 64) {
#pragma unroll
    for (int nb = 0; nb < 4; ++nb) b1[nb] = ldB(k0 + 32, nb);
    bf16x8 a0 = ldA(k0);
#pragma unroll
    for (int nb = 0; nb < 4; ++nb)
      acc[nb] = __builtin_amdgcn_mfma_f32_16x16x32_bf16(a0, b0[nb], acc[nb], 0, 0, 0);
    if (k0 + 64 < 256) {
#pragma unroll
      for (int nb = 0; nb < 4; ++nb) b0[nb] = ldB(k0 + 64, nb);
    }
    bf16x8 a1 = ldA(k0 + 32);
#pragma unroll
    for (int nb = 0; nb < 4; ++nb)
      acc[nb] = __builtin_amdgcn_mfma_f32_16x16x32_bf16(a1, b1[nb], acc[nb], 0, 0, 0);
  }
  __syncthreads();   // all At reads done before Ot overwrite

  // ---- phase 3: LN epilogue -> msgB ----
#pragma unroll
  for (int nb = 0; nb < 4; ++nb)
#pragma unroll
    for (int r = 0; r < 4; ++r)
      Ot[quad * 4 + r][wq * 64 + nb * 16 + l16] = acc[nb][r];
  __syncthreads();

#pragma unroll
  for (int rr = 0; rr < 4; ++rr) {
    const int row = rr * 4 + wq;
    float4 v = *(const float4*)&Ot[row][lane * 4];
    float mean, inv; row_stats(v, mean, inv);
    ushort4 u;
    u.x = f2b((v.x - mean) * inv); u.y = f2b((v.y - mean) * inv);
    u.z = f2b((v.z - mean) * inv); u.w = f2b((v.w - mean) * inv);
    *(ushort4*)(msgB + (size_t)(R0 + row) * 256 + lane * 4) = u;
  }
}

// ---------------- split-S MFMA flash attention: partial (transposed) -------
// Head-major QKV: Q|K|V segments of kOff elems each; within a segment
// [head nh][token][64]. Grid: (L/256, NHt, split), 512 threads = 8 waves x
// 2 q-blocks x 16 queries. S^T = K Q^T; softmax in exp2 domain in-register
// (raw v_exp_f32); P^T stays in registers (Vt pcol permutation). K tile
// staged cooperatively into XOR-swizzled fragment-order LDS; V per-wave
// (pcol). O^T = V^T P. l-sum on the MATRIX pipe: ones-A MFMA over the P
// fragments gives the full 64-key denominator. pO partials stored bf16.
// setprio(1) around MFMA clusters. LDS = 34816 B.
__global__ __launch_bounds__(512, 4) void k_attn_p(unsigned short* __restrict__ pO,
                                                   float* __restrict__ pML,
                                                   const unsigned short* __restrict__ QKV,
                                                   unsigned long long kOff,
                                                   int L, int S, int chunk) {
  __shared__ __align__(16) char smem[34816];
  unsigned short* Kl = (unsigned short*)smem;                            // [2][4096]
  unsigned short (*Vt)[64][72] = (unsigned short (*)[64][72])(smem + 16384);
  const int tid = threadIdx.x;
  const int wq = tid >> 6, lane = tid & 63;                // wq 0..7
  const int l16 = lane & 15, quad = lane >> 4;
  const int q0 = blockIdx.x * 256;
  const int nh = blockIdx.y, NHt = gridDim.y;
  const int s0 = blockIdx.z * chunk;
  const float S2 = 0.18033688f;   // 0.125 * log2(e) — softmax in exp2 domain

  const unsigned short* Qh = QKV + (size_t)nh * L * 64;
  const unsigned short* Kh = QKV + kOff + (size_t)nh * S * 64;
  const unsigned short* Vh = QKV + 2 * kOff + (size_t)nh * S * 64;

  // Q fragments: 2 q-blocks per wave (rows q0 + (qb*8+wq)*16 + l16)
  bf16x8 qa[2][2];
#pragma unroll
  for (int qb = 0; qb < 2; ++qb) {
    const unsigned short* qp = Qh + (size_t)(q0 + (qb * 8 + wq) * 16 + l16) * 64;
    qa[qb][0] = *(const bf16x8*)(qp + quad * 8);
    qa[qb][1] = *(const bf16x8*)(qp + 32 + quad * 8);
  }

  // ones A-fragment for the l-sum MFMA (bf16 1.0 = 0x3F80)
  const short ONE = (short)0x3F80;
  const bf16x8 onesv = (bf16x8){ONE, ONE, ONE, ONE, ONE, ONE, ONE, ONE};

  f32x4 acc[2][4];   // O^T per q-block
  f32x4 lacc[2];     // denominator: all 4 elems equal Σ_key P[key][q=l16]
#pragma unroll
  for (int qb = 0; qb < 2; ++qb) {
#pragma unroll
    for (int i = 0; i < 4; ++i) acc[qb][i] = (f32x4){0.f, 0.f, 0.f, 0.f};
    lacc[qb] = (f32x4){0.f, 0.f, 0.f, 0.f};
  }
  float m_[2] = {-1e30f, -1e30f};   // log2 domain

  // K cooperative staging: thread -> (key = tid>>3, dh0 = (tid&7)*8).
  // Fragment-order LDS with XOR swizzle: slot ^= ((f&1)<<2)|(slot>>4), which
  // on the writer side equals tid&7 — makes both the b128 write phases and
  // the b128 read phases 2-lanes-per-bank-group (conflict-free).
  const int skey = tid >> 3;
  const int sdh0 = (tid & 7) * 8;
  const int kidx = (((skey >> 4) * 2 + (sdh0 >> 5)) * 64 +
                    (((sdh0 >> 3) & 3) * 16) + ((skey & 15) ^ (tid & 7))) * 8;
  // K read slots (logical slot = lane): phys = lane ^ ((c<<2)|quad)
  const int krd0 = lane ^ quad;
  const int krd1 = lane ^ (4 | quad);
  // V per-wave staging: lane = key, wave wq covers dh rows [wq*8, wq*8+8)
  const int vdh0 = wq * 8;
  // permuted Vt column (pcol): key -> 32*(kb>>1) + 8*q' + 4*(kb&1) + r so the
  // PV MFMA k-slots are each lane quad's own scores.
  const int pc = ((lane >> 5) << 5) + (((lane >> 2) & 3) << 3)
               + (((lane >> 4) & 1) << 2) + (lane & 3);

  uint4 kv = *(const uint4*)(Kh + (size_t)(s0 + skey) * 64 + sdh0);
  uint4 va = *(const uint4*)(Vh + (size_t)(s0 + lane) * 64 + vdh0);
  *(uint4*)&Kl[kidx] = kv;
  {
    const unsigned short* pv = (const unsigned short*)&va;
#pragma unroll
    for (int i = 0; i < 8; ++i) Vt[0][vdh0 + i][pc] = pv[i];
  }
  if (chunk > 64) {
    kv = *(const uint4*)(Kh + (size_t)(s0 + 64 + skey) * 64 + sdh0);
    va = *(const uint4*)(Vh + (size_t)(s0 + 64 + lane) * 64 + vdh0);
  }
  __syncthreads();

  int cur = 0;
  for (int t = 0; t < chunk; t += 64) {
    // S^T tile = K Q^T; kf from swizzled fragment-order LDS
    f32x4 sc[2][4];
    const unsigned short* Klc = Kl + cur * 4096;
    __builtin_amdgcn_s_setprio(1);
#pragma unroll
    for (int kb = 0; kb < 4; ++kb) {
      bf16x8 kf0 = *(const bf16x8*)&Klc[((kb * 2 + 0) * 64 + krd0) * 8];
      bf16x8 kf1 = *(const bf16x8*)&Klc[((kb * 2 + 1) * 64 + krd1) * 8];
#pragma unroll
      for (int qb = 0; qb < 2; ++qb) {
        f32x4 z = (f32x4){0.f, 0.f, 0.f, 0.f};
        z = __builtin_amdgcn_mfma_f32_16x16x32_bf16(kf0, qa[qb][0], z, 0, 0, 0);
        z = __builtin_amdgcn_mfma_f32_16x16x32_bf16(kf1, qa[qb][1], z, 0, 0, 0);
        sc[qb][kb] = z;
      }
    }
    __builtin_amdgcn_s_setprio(0);
    // stage tile t+64 into the other buffer; then issue loads for t+128
    if (t + 64 < chunk) {
      *(uint4*)&Kl[(cur ^ 1) * 4096 + kidx] = kv;
      const unsigned short* pv = (const unsigned short*)&va;
#pragma unroll
      for (int i = 0; i < 8; ++i) Vt[cur ^ 1][vdh0 + i][pc] = pv[i];
    }
    if (t + 128 < chunk) {
      kv = *(const uint4*)(Kh + (size_t)(s0 + t + 128 + skey) * 64 + sdh0);
      va = *(const uint4*)(Vh + (size_t)(s0 + t + 128 + lane) * 64 + vdh0);
    }
    // online softmax per q-block (exp2 domain, raw v_exp) + in-register P pack
    union { bf16x8 v; unsigned int w[4]; } ps0[2], ps1[2];
#pragma unroll
    for (int qb = 0; qb < 2; ++qb) {
      f32x4 mv01, mv;
#pragma unroll
      for (int r = 0; r < 4; ++r) mv01[r] = fmaxf(sc[qb][0][r], sc[qb][1][r]);
#pragma unroll
      for (int r = 0; r < 4; ++r) mv[r] = fmaxf(mv01[r], fmaxf(sc[qb][2][r], sc[qb][3][r]));
      float mx = fmaxf(fmaxf(mv[0], mv[1]), fmaxf(mv[2], mv[3])) * S2;
      mx = fmaxf(mx, __shfl_xor(mx, 16));
      mx = fmaxf(mx, __shfl_xor(mx, 32));
      float mn;
      if (__all(mx <= m_[qb] + 8.f)) {
        mn = m_[qb];                      // defer-max: P bounded by 2^8, no rescale
      } else {
        mn = fmaxf(m_[qb], mx);
        float alpha = fexp2(m_[qb] - mn);
        m_[qb] = mn;
#pragma unroll
        for (int r = 0; r < 4; ++r) lacc[qb][r] *= alpha;
#pragma unroll
        for (int nb = 0; nb < 4; ++nb)
#pragma unroll
          for (int r = 0; r < 4; ++r) acc[qb][nb][r] *= alpha;
      }
#pragma unroll
      for (int kb = 0; kb < 4; ++kb)
#pragma unroll
        for (int r = 0; r < 4; ++r)
          sc[qb][kb][r] = fexp2(fmaf(sc[qb][kb][r], S2, -mn));
      ps0[qb].w[0] = pk2(sc[qb][0][0], sc[qb][0][1]);
      ps0[qb].w[1] = pk2(sc[qb][0][2], sc[qb][0][3]);
      ps0[qb].w[2] = pk2(sc[qb][1][0], sc[qb][1][1]);
      ps0[qb].w[3] = pk2(sc[qb][1][2], sc[qb][1][3]);
      ps1[qb].w[0] = pk2(sc[qb][2][0], sc[qb][2][1]);
      ps1[qb].w[1] = pk2(sc[qb][2][2], sc[qb][2][3]);
      ps1[qb].w[2] = pk2(sc[qb][3][0], sc[qb][3][1]);
      ps1[qb].w[3] = pk2(sc[qb][3][2], sc[qb][3][3]);
    }
    // O^T += V^T P (Vt columns pcol-permuted; vb shared across q-blocks);
    // l-sum on the matrix pipe: ones-A MFMA over ps0/ps1 sums all 64 keys.
    __builtin_amdgcn_s_setprio(1);
#pragma unroll
    for (int db = 0; db < 4; ++db) {
      bf16x8 vb0 = *(const bf16x8*)&Vt[cur][db * 16 + l16][quad * 8];
      bf16x8 vb1 = *(const bf16x8*)&Vt[cur][db * 16 + l16][32 + quad * 8];
#pragma unroll
      for (int qb = 0; qb < 2; ++qb) {
        acc[qb][db] = __builtin_amdgcn_mfma_f32_16x16x32_bf16(vb0, ps0[qb].v, acc[qb][db], 0, 0, 0);
        acc[qb][db] = __builtin_amdgcn_mfma_f32_16x16x32_bf16(vb1, ps1[qb].v, acc[qb][db], 0, 0, 0);
      }
    }
#pragma unroll
    for (int qb = 0; qb < 2; ++qb) {
      lacc[qb] = __builtin_amdgcn_mfma_f32_16x16x32_bf16(onesv, ps0[qb].v, lacc[qb], 0, 0, 0);
      lacc[qb] = __builtin_amdgcn_mfma_f32_16x16x32_bf16(onesv, ps1[qb].v, lacc[qb], 0, 0, 0);
    }
    __builtin_amdgcn_s_setprio(0);
    __syncthreads();
    cur ^= 1;
  }

  // epilogue: transpose O^T -> O via LDS (reuse smem as f32 [64][68]);
  // 4 passes: qb x wave-half; pO stored bf16.
  float* Ot = (float*)smem;
#pragma unroll
  for (int qb = 0; qb < 2; ++qb) {
#pragma unroll
    for (int pass = 0; pass < 2; ++pass) {
      __syncthreads();
      if ((wq >> 2) == pass) {
#pragma unroll
        for (int db = 0; db < 4; ++db)
          *(f32x4*)&Ot[(size_t)((wq & 3) * 16 + l16) * 68 + db * 16 + quad * 4] = acc[qb][db];
      }
      __syncthreads();
      if ((wq >> 2) == pass) {
#pragma unroll
        for (int i = 0; i < 16; ++i) {
          const int row = q0 + (qb * 8 + wq) * 16 + i;
          pO[((size_t)(blockIdx.z * NHt + nh) * L + row) * 64 + lane] =
              f2b(Ot[(size_t)((wq & 3) * 16 + i) * 68 + lane]);
        }
      }
    }
  }
  if (quad == 0) {
#pragma unroll
    for (int qb = 0; qb < 2; ++qb) {
      float* pml = pML + ((size_t)(blockIdx.z * NHt + nh) * L +
                          q0 + (qb * 8 + wq) * 16 + l16) * 2;
      pml[0] = m_[qb]; pml[1] = lacc[qb][0];
    }
  }
}

// ---------------- semantic gather, batched (index 2048 -> zeros) ------------
// 256 threads = 4 rows x 64; rows <8192 gather from src half with sIdx.
__global__ __launch_bounds__(256) void k_gather2(unsigned short* __restrict__ dst,
                                                 const float* __restrict__ sF,
                                                 const int* __restrict__ sIdx,
                                                 const int* __restrict__ tIdx) {
  const int row = blockIdx.x * 4 + (threadIdx.x >> 6);
  const int t = threadIdx.x & 63;
  const int half = row >> 13;
  const int r = row & 8191;
  const int g = r >> 9;
  const int b = g >> 3;               // mask_num = 8
  const int id = half ? tIdx[r] : sIdx[r];
  float4 v = {0.f, 0.f, 0.f, 0.f};
  if ((unsigned)id < 2048u) {
    const float* base = sF + (size_t)(half * 2 + b) * 524288;   // 2048*256
    v = ((const float4*)(base + (size_t)id * 256))[t];
  }
  ushort4 u; u.x = f2b(v.x); u.y = f2b(v.y); u.z = f2b(v.z); u.w = f2b(v.w);
  ((ushort4*)(dst + (size_t)row * 256))[t] = u;
}

// ---------------------------------------------------------------------------
extern "C" void kernel_launch(void* const* d_in, const int* in_sizes, int n_in,
                              void* d_out, int out_size, void* d_ws, size_t ws_size,
                              hipStream_t stream) {
  const void* src_feat = d_in[0];
  const void* tgt_feat = d_in[1];
  const int* s_sub = (const int*)d_in[6];
  const int* t_sub = (const int*)d_in[7];
  const void* src2d = d_in[11];
  const void* tgt2d = d_in[12];
  const void* dinoW = d_in[14];
  const void* qW = d_in[15];
  const void* kW = d_in[16];
  const void* vW = d_in[17];
  const void* mW = d_in[18];
  const void* w1 = d_in[19];
  const void* w2 = d_in[20];

  const int BIG = 1 << 30;
  char* p = (char*)d_ws;
  int* dflag = (int*)p;                       p += 256;
  float* sF = (float*)p;                      p += 4194304;   // [sF|tF] adjacent
  float* tF = (float*)p;                      p += 4194304;
  unsigned short* sB    = (unsigned short*)p; p += 2097152;   // [sB|tB] adjacent
  unsigned short* tB    = (unsigned short*)p; p += 2097152;
  unsigned short* s2B   = (unsigned short*)p; p += 2097152;   // [s2B|t2B] adjacent
  unsigned short* t2B   = (unsigned short*)p; p += 2097152;
  unsigned short* d2B   = (unsigned short*)p; p += 3145728;   // 4096x384 (reused)
  unsigned short* sSubB = (unsigned short*)p; p += 4194304;   // [sSub|tSub] adjacent
  unsigned short* tSubB = (unsigned short*)p; p += 4194304;
  // region A (25.2MB): qkvB (Q|K|V head-major) overlaid by msgB
  unsigned short* qkvB  = (unsigned short*)p;
  unsigned short* msgB  = (unsigned short*)(p + 8388608);     // A + 8.4MB  (8.4MB)
  p += 25165824;
  // region B (25.2MB): hB (16384x512)
  unsigned short* hB    = (unsigned short*)p;
  p += 25165824;
  unsigned short* WtD   = (unsigned short*)p; p += 196608;    // 256x384
  unsigned short* WtQKV = (unsigned short*)p; p += 1966080;   // 5x768x256
  unsigned short* WtM   = (unsigned short*)p; p += 655360;    // 5x256x256
  unsigned short* WtW1  = (unsigned short*)p; p += 2621440;   // 5x512x512
  unsigned short* WtW2  = (unsigned short*)p; p += 1310720;   // 5x256x512
  unsigned short* pO = (unsigned short*)p;    p += 16777216;  // split*NHt*L*64 bf16
  float* pML = (float*)p;                     p += 2097152;
  // total ~105 MB

  // probe dtype (qW ~ N(0, 1/16))
  k_probe<<<1, 256, 0, stream>>>(dflag, (const unsigned short*)qW, 4096);

  // weight transposes + fragment pack; QKV packed per layer (768 rows = 48
  // nblks; q at 0, k at +65536, v at +131072 elements — the packed layout's
  // per-16-col chunk is 4096 elems so sub-block bases are unchanged).
  k_wt<<<dim3(8, 12, 1), 256, 0, stream>>>(WtD, dinoW, 384, 256, 0, dflag);
  k_wt<<<dim3(8, 8, 5), 256, 0, stream>>>(WtQKV,          qW, 256, 256, 196608, dflag);
  k_wt<<<dim3(8, 8, 5), 256, 0, stream>>>(WtQKV + 65536,  kW, 256, 256, 196608, dflag);
  k_wt<<<dim3(8, 8, 5), 256, 0, stream>>>(WtQKV + 131072, vW, 256, 256, 196608, dflag);
  k_wt<<<dim3(8, 8, 5), 256, 0, stream>>>(WtM, mW, 256, 256, 65536, dflag);
  k_wt<<<dim3(16, 16, 5), 256, 0, stream>>>(WtW1, w1, 512, 512, 262144, dflag);
  k_wt<<<dim3(8, 16, 5), 256, 0, stream>>>(WtW2, w2, 512, 256, 131072, dflag);

  // One attention block: QKV (single dispatch, row-XOR for KV, head-major
  // output), partial, fused combine+M-proj+LN, FFN-W1, fused W2+LN+residual.
  auto attnB = [&](int l, const unsigned short* Abase, int rowOff, int rowXor,
                   int M, int L, int S, int split, int NHt,
                   float* xF, unsigned short* xB, size_t outOff) {
    const int lg = (L == 2048) ? 11 : 9;
    k_gmm<256><<<dim3(12, M / 64), 256, 0, stream>>>(
        qkvB, 768, Abase, 256, Abase, 256, 256,
        WtQKV + (size_t)l * 196608, 0, rowOff, rowXor, 256, lg);
    const int chunk = S / split;
    k_attn_p<<<dim3(L / 256, NHt, split), 512, 0, stream>>>(
        pO, pML, qkvB, (unsigned long long)M * 256, L, S, chunk);
    // fused combine + M-proj + LN -> msgB
    k_mprojc<<<M / 16, 256, 0, stream>>>(msgB, pO, pML, lg, split, NHt,
                                         WtM + (size_t)l * 65536);
    // FFN W1 (relu) -> hB
    k_gmm<512><<<dim3(8, M / 64), 256, 0, stream>>>(
        hB, 512, xB, 256, msgB, 256, 256, WtW1 + (size_t)l * 262144, 1, 0, 0, BIG, 0);
    // fused W2 + LN + residual
    if (xF) k_gmm_ln<512><<<M / 16, 256, 0, stream>>>(
        xB, xF, nullptr, 0, nullptr, hB, 512, WtW2 + (size_t)l * 131072, 1, dflag);
    else    k_gmm_ln<512><<<M / 16, 256, 0, stream>>>(
        nullptr, nullptr, d_out, outOff, xB, hB, 512, WtW2 + (size_t)l * 131072, 2, dflag);
  };

  // ---- init ----
  k_load2<<<1024, 256, 0, stream>>>(sF, sB, src_feat, 262144, dflag);
  k_load2<<<1024, 256, 0, stream>>>(tF, tB, tgt_feat, 262144, dflag);
  k_loadb<<<1536, 256, 0, stream>>>(d2B, src2d, 393216, dflag);
  k_gmm<384><<<dim3(4, 64), 256, 0, stream>>>(s2B, 256, d2B, 384, d2B, 384, 384,
                                              WtD, 0, 0, 0, BIG, 0);
  k_loadb<<<1536, 256, 0, stream>>>(d2B, tgt2d, 393216, dflag);
  k_gmm<384><<<dim3(4, 64), 256, 0, stream>>>(t2B, 256, d2B, 384, d2B, 384, 384,
                                              WtD, 0, 0, 0, BIG, 0);

  // layer 0: self, src+tgt batched (M=8192, NHt=16)
  k_add_dino<<<2048, 256, 0, stream>>>(sF, sB, s2B, 524288);
  attnB(0, sB, 0, 0, 8192, 2048, 2048, 4, 16, sF, sB, 0);
  // layer 1: cross (sequential): Q rows from x, KV rows = x^4096
  attnB(1, sB, 0,    4096, 4096, 2048, 2048, 8, 8, sF, sB, 0);
  attnB(1, sB, 4096, 4096, 4096, 2048, 2048, 8, 8, tF, tB, 0);
  // layer 2: self batched (+dino)
  k_add_dino<<<2048, 256, 0, stream>>>(sF, sB, s2B, 524288);
  attnB(2, sB, 0, 0, 8192, 2048, 2048, 4, 16, sF, sB, 0);
  // layer 3: cross
  attnB(3, sB, 0,    4096, 4096, 2048, 2048, 8, 8, sF, sB, 0);
  attnB(3, sB, 4096, 4096, 4096, 2048, 2048, 8, 8, tF, tB, 0);
  // semantic gather (batched, pad index 2048 -> zeros)
  k_gather2<<<4096, 256, 0, stream>>>(sSubB, sF, s_sub, t_sub);
  // layer 4: semantic subspace cross, both directions batched (M=16384,
  // NHt=128, KV rows = rows ^ 8192 -> opposite subset)
  attnB(4, sSubB, 0, 8192, 16384, 512, 512, 2, 128, nullptr, sSubB, 2097152);

  // main outputs (sF|tF contiguous -> out[0..2097152))
  k_store<<<2048, 256, 0, stream>>>(d_out, 0, sF, 524288, dflag);
}